// Round 12
// baseline (1643.766 us; speedup 1.0000x reference)
//
#include <hip/hip_runtime.h>
#include <hip/hip_bf16.h>
#include <math.h>

typedef __bf16 bf16x8 __attribute__((ext_vector_type(8)));
typedef float  f32x4  __attribute__((ext_vector_type(4)));

#define GAS(p) ((const __attribute__((address_space(1))) void*)(p))
#define LAS(p) ((__attribute__((address_space(3))) void*)(p))

static constexpr int NE = 768;

// ---------------- embed: x = tok_emb[idx] + pos_emb, -> bf16 ----------------
__global__ __launch_bounds__(256) void k_embed(const int* __restrict__ idx,
    const float* __restrict__ tok, const float* __restrict__ pos,
    __hip_bfloat16* __restrict__ xb)
{
    int bt = blockIdx.x;            // 0..8191
    int t  = bt & 2047;
    int token = idx[bt];
    const float* te = tok + (size_t)token * NE;
    const float* pe = pos + (size_t)t * NE;
    __hip_bfloat16* o = xb + (size_t)bt * NE;
    for (int c = threadIdx.x; c < NE; c += 256)
        o[c] = __float2bfloat16(te[c] + pe[c]);
}

// ------------- transpose fp32 [R][C] -> bf16 [outRows][R] (zero-pad) -------------
__global__ __launch_bounds__(256) void k_transpose_f32_bf16(
    const float* __restrict__ in, __hip_bfloat16* __restrict__ out,
    int R, int C, int outRows)
{
    __shared__ float tile[32][33];
    int c0 = blockIdx.x * 32, r0 = blockIdx.y * 32;
    int tx = threadIdx.x & 31, ty = threadIdx.x >> 5;
    #pragma unroll
    for (int i = 0; i < 32; i += 8) {
        int r = r0 + ty + i, c = c0 + tx;
        tile[ty + i][tx] = (r < R && c < C) ? in[(size_t)r * C + c] : 0.f;
    }
    __syncthreads();
    #pragma unroll
    for (int i = 0; i < 32; i += 8) {
        int oc = c0 + ty + i, orr = r0 + tx;
        if (oc < outRows && orr < R)
            out[(size_t)oc * R + orr] = __float2bfloat16(tile[tx][ty + i]);
    }
}

// ------------- batched bf16 transpose: in [z][R][C] -> out [z][C][R] -------------
__global__ __launch_bounds__(256) void k_transpose_bf16(
    const __hip_bfloat16* __restrict__ in, __hip_bfloat16* __restrict__ out,
    int R, int C)
{
    __shared__ __hip_bfloat16 tile[32][33];
    size_t boff = (size_t)blockIdx.z * R * C;
    int c0 = blockIdx.x * 32, r0 = blockIdx.y * 32;
    int tx = threadIdx.x & 31, ty = threadIdx.x >> 5;
    #pragma unroll
    for (int i = 0; i < 32; i += 8)
        tile[ty + i][tx] = in[boff + (size_t)(r0 + ty + i) * C + (c0 + tx)];
    __syncthreads();
    #pragma unroll
    for (int i = 0; i < 32; i += 8)
        out[boff + (size_t)(c0 + ty + i) * R + (r0 + tx)] = tile[tx][ty + i];
}

__global__ __launch_bounds__(256) void k_pack_bias(const float* __restrict__ bq,
    const float* __restrict__ bk, const float* __restrict__ bv, float* __restrict__ o)
{
    int i = blockIdx.x * 256 + threadIdx.x;
    if (i < 768) o[i] = bq[i];
    else if (i < 1536) o[i] = bk[i - 768];
    else if (i < 2304) o[i] = bv[i - 1536];
}

// ---------------- m97-style 128x128 bf16 MFMA GEMM (qkv/att/PV) ----------------
template<int MODE>
__global__ __launch_bounds__(256) void k_gemm(
    const __hip_bfloat16* __restrict__ A, const __hip_bfloat16* __restrict__ Bt,
    int K, int lda, int ldb,
    size_t strideA, size_t strideB, size_t strideC,
    float* __restrict__ outf, int ldc, int ncols,
    const float* __restrict__ bias, float scale,
    __hip_bfloat16* __restrict__ oq, __hip_bfloat16* __restrict__ ok,
    __hip_bfloat16* __restrict__ ov)
{
    int bn = blockIdx.x, bm = blockIdx.y, bz = blockIdx.z;
    if constexpr (MODE == 2) bm = (int)gridDim.y - 1 - bm;   // longest-first dispatch
    if (MODE == 1 && bn > bm) return;   // fully masked causal tile
    __shared__ __align__(16) __hip_bfloat16 As[128 * 32];
    __shared__ __align__(16) __hip_bfloat16 Bs[128 * 32];
    const __hip_bfloat16* Ab = A  + bz * strideA + (size_t)bm * 128 * lda;
    const __hip_bfloat16* Bb = Bt + bz * strideB + (size_t)bn * 128 * ldb;
    int tid = threadIdx.x, w = tid >> 6, lane = tid & 63;
    int wr = w >> 1, wc = w & 1;
    f32x4 acc[4][4] = {};
    int sr = tid >> 2, sc = (tid & 3) * 8;
    int lr = lane & 15, lk = (lane >> 4) * 8;

    const int kend = (MODE == 2) ? (bm + 1) * 128 : K;   // causal K-truncation for PV

    for (int k0 = 0; k0 < kend; k0 += 32) {
        __syncthreads();
        #pragma unroll
        for (int i = 0; i < 2; ++i) {
            __builtin_amdgcn_global_load_lds(GAS(Ab + (size_t)(i * 64 + sr) * lda + k0 + sc),
                                             LAS((char*)As + i * 4096 + w * 1024), 16, 0, 0);
            __builtin_amdgcn_global_load_lds(GAS(Bb + (size_t)(i * 64 + sr) * ldb + k0 + sc),
                                             LAS((char*)Bs + i * 4096 + w * 1024), 16, 0, 0);
        }
        __syncthreads();
        bf16x8 af[4], bfv[4];
        #pragma unroll
        for (int mi = 0; mi < 4; ++mi)
            af[mi] = *(const bf16x8*)(As + (wr * 64 + mi * 16 + lr) * 32 + lk);
        #pragma unroll
        for (int ni = 0; ni < 4; ++ni)
            bfv[ni] = *(const bf16x8*)(Bs + (wc * 64 + ni * 16 + lr) * 32 + lk);
        #pragma unroll
        for (int mi = 0; mi < 4; ++mi)
            #pragma unroll
            for (int ni = 0; ni < 4; ++ni)
                acc[mi][ni] = __builtin_amdgcn_mfma_f32_16x16x32_bf16(af[mi], bfv[ni], acc[mi][ni], 0, 0, 0);
    }

    int r4 = (lane >> 4) * 4;
    #pragma unroll
    for (int mi = 0; mi < 4; ++mi) {
        #pragma unroll
        for (int ni = 0; ni < 4; ++ni) {
            #pragma unroll
            for (int r = 0; r < 4; ++r) {
                int row = bm * 128 + wr * 64 + mi * 16 + r4 + r;
                int col = bn * 128 + wc * 64 + ni * 16 + lr;
                float v = acc[mi][ni][r];
                if constexpr (MODE == 0) {
                    v += bias[col];
                    __hip_bfloat16 h = __float2bfloat16(v);
                    if (col < 768)       oq[(size_t)row * 768 + col]          = h;
                    else if (col < 1536) ok[(size_t)row * 768 + (col - 768)]  = h;
                    else                 ov[(size_t)row * 768 + (col - 1536)] = h;
                } else if constexpr (MODE == 1) {
                    outf[bz * strideC + (size_t)row * ldc + col] = v * scale;
                } else {
                    outf[bz * strideC + (size_t)row * ldc + col] = v;
                }
            }
        }
    }
}

// ================= 128x128 head GEMM, BK=64, dbuf, counted vmcnt, 2 blocks/CU =================
// out[8192][V] = A[8192][768]*Bt[50432][768]^T + bias. 4 waves (2M x 2N), each 64x64.
// LDS = (A 128x64 + B 128x64) x 2buf = 64 KiB exactly -> 2 blocks/CU; co-resident
// block overlaps this block's epilogue (262KB fp32 store ~= 40% of block time at
// 1 block/CU — the measured binder) and residual stalls.
// Per K-tile: reads(p) -> barrier1 -> stage(kt+2 -> p) -> vmcnt(8) -> barrier2 ->
// 32 MFMA (setprio). vmcnt never drains to 0 in the loop (R11's failure); per-wave
// vmcnt(8) + barrier2 = collective guarantee tile kt+1 landed (each wave stages its
// own 8 loads/tile). Addressing/swizzle identical to R6/R9 (proven, 0 conflicts).
__global__ __launch_bounds__(256, 2) void k_gemm_head(
    const __hip_bfloat16* __restrict__ A,   // [8192][768]
    const __hip_bfloat16* __restrict__ Bt,  // [50432][768]
    float* __restrict__ out, const float* __restrict__ bias, int ldc, int ncols)
{
    constexpr int K = 768, NT = K / 64;     // 12 K-tiles
    __shared__ __align__(16) __hip_bfloat16 As[2][128 * 64];
    __shared__ __align__(16) __hip_bfloat16 Bs[2][128 * 64];

    const int bm = blockIdx.x, bn = blockIdx.y;   // bm fastest -> B-panel L2/L3 reuse
    const int tid = threadIdx.x;
    const int w = tid >> 6, lane = tid & 63;
    const int wr = w >> 1, wc = w & 1;            // wave tile: rows wr*64, cols wc*64
    const int lr = lane & 15, lu = lane >> 4;

    const int sr = tid >> 3;                      // staging row (32-row chunk per l)
    const int su = (tid & 7) ^ (sr & 7);          // pre-swizzled source 16B unit
    const __hip_bfloat16* Ap = A  + (size_t)(bm * 128) * K;
    const __hip_bfloat16* Bp = Bt + (size_t)(bn * 128) * K;

    f32x4 acc[4][4] = {};

    auto stage = [&](int kt, int pb) {            // 8 loads/thread: 4 A rows-chunks + 4 B
        #pragma unroll
        for (int l = 0; l < 4; ++l) {
            int v = l * 256 + tid;
            int row = v >> 3, u = (v & 7) ^ (row & 7);
            __builtin_amdgcn_global_load_lds(GAS(Ap + (size_t)row * K + kt * 64 + u * 8),
                                             LAS(&As[pb][v * 8]), 16, 0, 0);
        }
        #pragma unroll
        for (int l = 0; l < 4; ++l) {
            int v = l * 256 + tid;
            int row = v >> 3, u = (v & 7) ^ (row & 7);
            __builtin_amdgcn_global_load_lds(GAS(Bp + (size_t)row * K + kt * 64 + u * 8),
                                             LAS(&Bs[pb][v * 8]), 16, 0, 0);
        }
    };
    auto rdA = [&](int pb, int m, int kk) {
        int row = wr * 64 + m * 16 + lr;
        return *(const bf16x8*)&As[pb][row * 64 + (((kk * 4 + lu) ^ (row & 7)) << 3)];
    };
    auto rdB = [&](int pb, int n, int kk) {
        int row = wc * 64 + n * 16 + lr;
        return *(const bf16x8*)&Bs[pb][row * 64 + (((kk * 4 + lu) ^ (row & 7)) << 3)];
    };

    // prologue: tiles 0,1 (16 loads/thread-wave total); gate tile 0 (8 newest = tile 1)
    stage(0, 0);
    stage(1, 1);
    asm volatile("s_waitcnt vmcnt(8)" ::: "memory");
    asm volatile("s_barrier" ::: "memory");

    for (int kt = 0; kt < NT; ++kt) {
        const int p = kt & 1;
        bf16x8 af[4][2], bfv[4][2];
        #pragma unroll
        for (int m = 0; m < 4; ++m) { af[m][0] = rdA(p, m, 0); af[m][1] = rdA(p, m, 1); }
        #pragma unroll
        for (int n = 0; n < 4; ++n) { bfv[n][0] = rdB(p, n, 0); bfv[n][1] = rdB(p, n, 1); }
        asm volatile("s_waitcnt lgkmcnt(0)" ::: "memory");  // frags in regs; buf[p] dead
        asm volatile("s_barrier" ::: "memory");             // all waves done with buf[p]
        if (kt + 2 < NT) {
            stage(kt + 2, p);                               // overwrite freed buffer
            asm volatile("s_waitcnt vmcnt(8)" ::: "memory");   // tile kt+1 landed (own 8)
        } else if (kt + 1 < NT) {
            asm volatile("s_waitcnt vmcnt(0)" ::: "memory");   // last prefetch landed
        }
        asm volatile("s_barrier" ::: "memory");             // collective: kt+1 visible
        __builtin_amdgcn_s_setprio(1);
        #pragma unroll
        for (int m = 0; m < 4; ++m)
            #pragma unroll
            for (int n = 0; n < 4; ++n)
                acc[m][n] = __builtin_amdgcn_mfma_f32_16x16x32_bf16(af[m][0], bfv[n][0], acc[m][n], 0, 0, 0);
        #pragma unroll
        for (int m = 0; m < 4; ++m)
            #pragma unroll
            for (int n = 0; n < 4; ++n)
                acc[m][n] = __builtin_amdgcn_mfma_f32_16x16x32_bf16(af[m][1], bfv[n][1], acc[m][n], 0, 0, 0);
        __builtin_amdgcn_s_setprio(0);
    }

    // epilogue: C-write with bias, col-bounded (overlapped by co-resident block)
    const int r4 = lu * 4;
    #pragma unroll
    for (int m = 0; m < 4; ++m) {
        #pragma unroll
        for (int n = 0; n < 4; ++n) {
            int col = bn * 128 + wc * 64 + n * 16 + lr;
            if (col < ncols) {
                float bv_ = bias[col];
                #pragma unroll
                for (int r = 0; r < 4; ++r) {
                    int row = bm * 128 + wr * 64 + m * 16 + r4 + r;
                    out[(size_t)row * ldc + col] = acc[m][n][r] + bv_;
                }
            }
        }
    }
}

// ---------------- causal softmax: float4 loads, __expf, zero-fill to 128-boundary ----------------
__global__ __launch_bounds__(256) void k_softmax(const float* __restrict__ att,
    __hip_bfloat16* __restrict__ P, int T)
{
    int t = blockIdx.x, b = blockIdx.y;
    const float* row = att + ((size_t)b * T + t) * T;
    __hip_bfloat16* prow = P + ((size_t)b * T + t) * T;
    const int n = t + 1;
    const int nz = ((t >> 7) + 1) << 7;     // PV (truncated) reads only cols < nz
    __shared__ float red[256];
    float4 v[2];
    float mx = -1e30f;
    #pragma unroll
    for (int j = 0; j < 2; ++j) {
        int e = (threadIdx.x + j * 256) * 4;
        v[j] = *(const float4*)(row + e);
        #pragma unroll
        for (int k = 0; k < 4; ++k)
            if (e + k < n) mx = fmaxf(mx, ((const float*)&v[j])[k]);
    }
    red[threadIdx.x] = mx; __syncthreads();
    for (int o = 128; o > 0; o >>= 1) {
        if (threadIdx.x < o) red[threadIdx.x] = fmaxf(red[threadIdx.x], red[threadIdx.x + o]);
        __syncthreads();
    }
    mx = red[0]; __syncthreads();
    float ev[8];
    float sum = 0.f;
    #pragma unroll
    for (int j = 0; j < 2; ++j) {
        int e = (threadIdx.x + j * 256) * 4;
        #pragma unroll
        for (int k = 0; k < 4; ++k) {
            float x = ((const float*)&v[j])[k];
            float ex = (e + k < n) ? __expf(x - mx) : 0.f;
            ev[j * 4 + k] = ex;
            sum += ex;
        }
    }
    red[threadIdx.x] = sum; __syncthreads();
    for (int o = 128; o > 0; o >>= 1) {
        if (threadIdx.x < o) red[threadIdx.x] += red[threadIdx.x + o];
        __syncthreads();
    }
    float inv = 1.f / red[0];
    #pragma unroll
    for (int j = 0; j < 2; ++j) {
        int e = (threadIdx.x + j * 256) * 4;
        #pragma unroll
        for (int k = 0; k < 4; ++k)
            if (e + k < nz) prow[e + k] = __float2bfloat16(ev[j * 4 + k] * inv);
    }
}

// ---------------- LayerNorm (eps 1e-5) fp32 -> bf16 ----------------
__global__ __launch_bounds__(256) void k_layernorm(const float* __restrict__ y,
    const float* __restrict__ g, const float* __restrict__ b,
    __hip_bfloat16* __restrict__ yn)
{
    int row = blockIdx.x;
    const float* yr = y + (size_t)row * NE;
    float s = 0.f, s2 = 0.f;
    for (int c = threadIdx.x; c < NE; c += 256) { float v = yr[c]; s += v; s2 += v * v; }
    __shared__ float r1[256], r2[256];
    r1[threadIdx.x] = s; r2[threadIdx.x] = s2; __syncthreads();
    for (int o = 128; o > 0; o >>= 1) {
        if (threadIdx.x < o) { r1[threadIdx.x] += r1[threadIdx.x + o]; r2[threadIdx.x] += r2[threadIdx.x + o]; }
        __syncthreads();
    }
    float mu = r1[0] / NE;
    float var = r2[0] / NE - mu * mu;
    float rs = rsqrtf(var + 1e-5f);
    __hip_bfloat16* o = yn + (size_t)row * NE;
    for (int c = threadIdx.x; c < NE; c += 256)
        o[c] = __float2bfloat16((yr[c] - mu) * rs * g[c] + b[c]);
}

extern "C" void kernel_launch(void* const* d_in, const int* in_sizes, int n_in,
                              void* d_out, int out_size, void* d_ws, size_t ws_size,
                              hipStream_t stream)
{
    const int*   idx  = (const int*)  d_in[0];
    const float* tok  = (const float*)d_in[1];
    const float* pos  = (const float*)d_in[2];
    const float* Wq   = (const float*)d_in[3];
    const float* bq   = (const float*)d_in[4];
    const float* Wk   = (const float*)d_in[5];
    const float* bk   = (const float*)d_in[6];
    const float* Wv   = (const float*)d_in[7];
    const float* bv   = (const float*)d_in[8];
    const float* ln_g = (const float*)d_in[9];
    const float* ln_b = (const float*)d_in[10];
    const float* Wh   = (const float*)d_in[11];
    const float* bh   = (const float*)d_in[12];
    float* out = (float*)d_out;

    const int B = 4, T = 2048, C = 768, V = 50257, Vp = 50432;  // Vp = 394*128

    char* p = (char*)d_ws;
    auto take = [&](size_t bytes) { char* r = p; p += (bytes + 255) & ~(size_t)255; return r; };
    __hip_bfloat16* xb    = (__hip_bfloat16*)take((size_t)B * T * C * 2);
    __hip_bfloat16* wqkvT = (__hip_bfloat16*)take((size_t)3 * C * C * 2);
    float*          bqkv  = (float*)take((size_t)3 * C * 4);
    __hip_bfloat16* qb    = (__hip_bfloat16*)take((size_t)B * T * C * 2);
    __hip_bfloat16* kb    = (__hip_bfloat16*)take((size_t)B * T * C * 2);
    __hip_bfloat16* vb    = (__hip_bfloat16*)take((size_t)B * T * C * 2);
    __hip_bfloat16* vT    = (__hip_bfloat16*)take((size_t)B * T * C * 2);
    float*          att   = (float*)take((size_t)B * T * T * 4);
    __hip_bfloat16* P     = (__hip_bfloat16*)take((size_t)B * T * T * 2);
    float*          y     = (float*)take((size_t)B * T * C * 4);
    __hip_bfloat16* yn    = (__hip_bfloat16*)take((size_t)B * T * C * 2);
    // Wh^T (77.4 MB, Vp rows) reuses the att+P region (100.6 MB) — dead once y exists.
    __hip_bfloat16* whT   = (__hip_bfloat16*)att;

    float scale = 1.0f / sqrtf((float)C);

    k_embed<<<dim3(B * T), 256, 0, stream>>>(idx, tok, pos, xb);
    k_transpose_f32_bf16<<<dim3(24, 24), 256, 0, stream>>>(Wq, wqkvT,             C, C, C);
    k_transpose_f32_bf16<<<dim3(24, 24), 256, 0, stream>>>(Wk, wqkvT + C * C,     C, C, C);
    k_transpose_f32_bf16<<<dim3(24, 24), 256, 0, stream>>>(Wv, wqkvT + 2 * C * C, C, C, C);
    k_pack_bias<<<dim3(9), 256, 0, stream>>>(bq, bk, bv, bqkv);

    // qkv: [8192,768] x [2304,768]^T
    k_gemm<0><<<dim3(18, 64, 1), 256, 0, stream>>>(xb, wqkvT, C, C, C, 0, 0, 0,
        nullptr, 0, 0, bqkv, 1.f, qb, kb, vb);

    k_transpose_bf16<<<dim3(24, 64, B), 256, 0, stream>>>(vb, vT, T, C);

    // att = q k^T / sqrt(C): per batch [2048,768] x [2048,768]^T (causal block skip)
    k_gemm<1><<<dim3(16, 16, B), 256, 0, stream>>>(qb, kb, C, C, C,
        (size_t)T * C, (size_t)T * C, (size_t)T * T, att, T, 0, nullptr, scale,
        nullptr, nullptr, nullptr);

    k_softmax<<<dim3(T, B), 256, 0, stream>>>(att, P, T);

    // y = P v: per batch [2048,2048] x [768,2048]^T, K truncated causally, longest-first
    k_gemm<2><<<dim3(6, 16, B), 256, 0, stream>>>(P, vT, T, T, T,
        (size_t)T * T, (size_t)C * T, (size_t)T * C, y, C, 0, nullptr, 1.f,
        nullptr, nullptr, nullptr);

    // Wh^T after PV so it can overwrite att/P scratch
    k_transpose_f32_bf16<<<dim3(Vp / 32, 24), 256, 0, stream>>>(Wh, whT, C, V, Vp);

    k_layernorm<<<dim3(B * T), 256, 0, stream>>>(y, ln_g, ln_b, yn);

    // logits: [8192,768] x [50432,768]^T -> fp32 d_out; 128^2 dbuf kernel, 2 blocks/CU
    // grid: bm fastest (x=64) so co-resident blocks share a B-panel
    k_gemm_head<<<dim3(64, Vp / 128), 256, 0, stream>>>(yn, whT, out, bh, V, V);
}

// Round 13
// 1212.603 us; speedup vs baseline: 1.3556x; 1.3556x over previous
//
#include <hip/hip_runtime.h>
#include <hip/hip_bf16.h>
#include <math.h>

typedef __bf16 bf16x8 __attribute__((ext_vector_type(8)));
typedef float  f32x4  __attribute__((ext_vector_type(4)));

#define GAS(p) ((const __attribute__((address_space(1))) void*)(p))
#define LAS(p) ((__attribute__((address_space(3))) void*)(p))

static constexpr int NE = 768;

// ---------------- embed: x = tok_emb[idx] + pos_emb, -> bf16 ----------------
__global__ __launch_bounds__(256) void k_embed(const int* __restrict__ idx,
    const float* __restrict__ tok, const float* __restrict__ pos,
    __hip_bfloat16* __restrict__ xb)
{
    int bt = blockIdx.x;            // 0..8191
    int t  = bt & 2047;
    int token = idx[bt];
    const float* te = tok + (size_t)token * NE;
    const float* pe = pos + (size_t)t * NE;
    __hip_bfloat16* o = xb + (size_t)bt * NE;
    for (int c = threadIdx.x; c < NE; c += 256)
        o[c] = __float2bfloat16(te[c] + pe[c]);
}

// ------------- transpose fp32 [R][C] -> bf16 [outRows][R] (zero-pad) -------------
__global__ __launch_bounds__(256) void k_transpose_f32_bf16(
    const float* __restrict__ in, __hip_bfloat16* __restrict__ out,
    int R, int C, int outRows)
{
    __shared__ float tile[32][33];
    int c0 = blockIdx.x * 32, r0 = blockIdx.y * 32;
    int tx = threadIdx.x & 31, ty = threadIdx.x >> 5;
    #pragma unroll
    for (int i = 0; i < 32; i += 8) {
        int r = r0 + ty + i, c = c0 + tx;
        tile[ty + i][tx] = (r < R && c < C) ? in[(size_t)r * C + c] : 0.f;
    }
    __syncthreads();
    #pragma unroll
    for (int i = 0; i < 32; i += 8) {
        int oc = c0 + ty + i, orr = r0 + tx;
        if (oc < outRows && orr < R)
            out[(size_t)oc * R + orr] = __float2bfloat16(tile[tx][ty + i]);
    }
}

// ------------- batched bf16 transpose: in [z][R][C] -> out [z][C][R] -------------
__global__ __launch_bounds__(256) void k_transpose_bf16(
    const __hip_bfloat16* __restrict__ in, __hip_bfloat16* __restrict__ out,
    int R, int C)
{
    __shared__ __hip_bfloat16 tile[32][33];
    size_t boff = (size_t)blockIdx.z * R * C;
    int c0 = blockIdx.x * 32, r0 = blockIdx.y * 32;
    int tx = threadIdx.x & 31, ty = threadIdx.x >> 5;
    #pragma unroll
    for (int i = 0; i < 32; i += 8)
        tile[ty + i][tx] = in[boff + (size_t)(r0 + ty + i) * C + (c0 + tx)];
    __syncthreads();
    #pragma unroll
    for (int i = 0; i < 32; i += 8)
        out[boff + (size_t)(c0 + ty + i) * R + (r0 + tx)] = tile[tx][ty + i];
}

__global__ __launch_bounds__(256) void k_pack_bias(const float* __restrict__ bq,
    const float* __restrict__ bk, const float* __restrict__ bv, float* __restrict__ o)
{
    int i = blockIdx.x * 256 + threadIdx.x;
    if (i < 768) o[i] = bq[i];
    else if (i < 1536) o[i] = bk[i - 768];
    else if (i < 2304) o[i] = bv[i - 1536];
}

// ---------------- m97-style 128x128 bf16 MFMA GEMM (qkv/att/PV) ----------------
template<int MODE>
__global__ __launch_bounds__(256) void k_gemm(
    const __hip_bfloat16* __restrict__ A, const __hip_bfloat16* __restrict__ Bt,
    int K, int lda, int ldb,
    size_t strideA, size_t strideB, size_t strideC,
    float* __restrict__ outf, int ldc, int ncols,
    const float* __restrict__ bias, float scale,
    __hip_bfloat16* __restrict__ oq, __hip_bfloat16* __restrict__ ok,
    __hip_bfloat16* __restrict__ ov)
{
    int bn = blockIdx.x, bm = blockIdx.y, bz = blockIdx.z;
    if constexpr (MODE == 2) bm = (int)gridDim.y - 1 - bm;   // longest-first dispatch
    if (MODE == 1 && bn > bm) return;   // fully masked causal tile
    __shared__ __align__(16) __hip_bfloat16 As[128 * 32];
    __shared__ __align__(16) __hip_bfloat16 Bs[128 * 32];
    const __hip_bfloat16* Ab = A  + bz * strideA + (size_t)bm * 128 * lda;
    const __hip_bfloat16* Bb = Bt + bz * strideB + (size_t)bn * 128 * ldb;
    int tid = threadIdx.x, w = tid >> 6, lane = tid & 63;
    int wr = w >> 1, wc = w & 1;
    f32x4 acc[4][4] = {};
    int sr = tid >> 2, sc = (tid & 3) * 8;
    int lr = lane & 15, lk = (lane >> 4) * 8;

    const int kend = (MODE == 2) ? (bm + 1) * 128 : K;   // causal K-truncation for PV

    for (int k0 = 0; k0 < kend; k0 += 32) {
        __syncthreads();
        #pragma unroll
        for (int i = 0; i < 2; ++i) {
            __builtin_amdgcn_global_load_lds(GAS(Ab + (size_t)(i * 64 + sr) * lda + k0 + sc),
                                             LAS((char*)As + i * 4096 + w * 1024), 16, 0, 0);
            __builtin_amdgcn_global_load_lds(GAS(Bb + (size_t)(i * 64 + sr) * ldb + k0 + sc),
                                             LAS((char*)Bs + i * 4096 + w * 1024), 16, 0, 0);
        }
        __syncthreads();
        bf16x8 af[4], bfv[4];
        #pragma unroll
        for (int mi = 0; mi < 4; ++mi)
            af[mi] = *(const bf16x8*)(As + (wr * 64 + mi * 16 + lr) * 32 + lk);
        #pragma unroll
        for (int ni = 0; ni < 4; ++ni)
            bfv[ni] = *(const bf16x8*)(Bs + (wc * 64 + ni * 16 + lr) * 32 + lk);
        #pragma unroll
        for (int mi = 0; mi < 4; ++mi)
            #pragma unroll
            for (int ni = 0; ni < 4; ++ni)
                acc[mi][ni] = __builtin_amdgcn_mfma_f32_16x16x32_bf16(af[mi], bfv[ni], acc[mi][ni], 0, 0, 0);
    }

    int r4 = (lane >> 4) * 4;
    #pragma unroll
    for (int mi = 0; mi < 4; ++mi) {
        #pragma unroll
        for (int ni = 0; ni < 4; ++ni) {
            #pragma unroll
            for (int r = 0; r < 4; ++r) {
                int row = bm * 128 + wr * 64 + mi * 16 + r4 + r;
                int col = bn * 128 + wc * 64 + ni * 16 + lr;
                float v = acc[mi][ni][r];
                if constexpr (MODE == 0) {
                    v += bias[col];
                    __hip_bfloat16 h = __float2bfloat16(v);
                    if (col < 768)       oq[(size_t)row * 768 + col]          = h;
                    else if (col < 1536) ok[(size_t)row * 768 + (col - 768)]  = h;
                    else                 ov[(size_t)row * 768 + (col - 1536)] = h;
                } else if constexpr (MODE == 1) {
                    outf[bz * strideC + (size_t)row * ldc + col] = v * scale;
                } else {
                    outf[bz * strideC + (size_t)row * ldc + col] = v;
                }
            }
        }
    }
}

// ================= 256x256 head GEMM — 8-phase template, single-barrier phases =================
// R9 base (best measured). Change: VM-less phases use ONE barrier {reads, stage, MFMA, BAR}
// — safe because each wave's ds_reads are drained (compiler lgkm) by its MFMA before the
// end-barrier, and every stage targets a region freed >=1 barrier after its last read.
// VM phases (ph3/ph7) keep {stage, VM4, BAR, MFMA, BAR}: the mid-barrier makes the
// per-wave vmcnt(4) a collective landing guarantee. 10 barriers / 2 K-tiles (was 16);
// waves desynchronize within phases -> MFMA overlaps other waves' ds_reads.
// In-flight ledger (per wave, insts): iter-start 4 [B(t1)]; ph0 +4 [A(t1)]; ph1/ph2 +2+2
// [B(t0+2)]; ph3 VM4 retires B(t1)+A(t1); ph4/5 +2+2 [A(t0+2)]; ph6/7 +2+2 [B(t1+2)];
// ph7 VM4 retires B(t0+2)+A(t0+2) -> invariant 4. Prologue: 12 loads, VM4 retires tile-0's 8.
__global__ __launch_bounds__(512, 2) void k_gemm_head(
    const __hip_bfloat16* __restrict__ A,   // [8192][768]
    const __hip_bfloat16* __restrict__ Bt,  // [50432][768]
    float* __restrict__ out, const float* __restrict__ bias, int ldc, int ncols)
{
    constexpr int K = 768, NT = K / 64, NI = NT / 2;    // 12 tiles, 6 iters
    __shared__ __align__(16) __hip_bfloat16 As[2][2][128 * 64];  // [buf][half]
    __shared__ __align__(16) __hip_bfloat16 Bs[2][2][128 * 64];

    // bijective XCD remap of fast axis (R6-measured +6%)
    const int Nx = (int)gridDim.x;
    const int qq = Nx >> 3, rr = Nx & 7;
    const int xcd = (int)blockIdx.x & 7, xidx = (int)blockIdx.x >> 3;
    const int bn = (xcd < rr ? xcd * (qq + 1) : rr * (qq + 1) + (xcd - rr) * qq) + xidx;
    const int bm = blockIdx.y;
    const int tid = threadIdx.x;
    const int w = tid >> 6, lane = tid & 63;
    const int wr = w >> 2, wc = w & 3;      // wave = (M-half wr, N-quarter wc)
    const int lr = lane & 15, lu = lane >> 4;

    const int sr = tid >> 3;                // staging row within 64-row chunk
    const int su = (tid & 7) ^ (sr & 7);    // pre-swizzled source 16B unit
    const __hip_bfloat16* Ap = A  + (size_t)(bm * 256) * K;
    const __hip_bfloat16* Bp = Bt + (size_t)(bn * 256) * K;

    f32x4 acc[8][4] = {};
    bf16x8 bq[4][2];

    auto stageAh = [&](int t, int h) {      // A half h (128 rows x 64) -> buf t&1
        #pragma unroll
        for (int l = 0; l < 2; ++l)
            __builtin_amdgcn_global_load_lds(
                GAS(Ap + (size_t)(h * 128 + l * 64 + sr) * K + t * 64 + su * 8),
                LAS(&As[t & 1][h][l * 4096 + tid * 8]), 16, 0, 0);
    };
    auto stageBh = [&](int t, int h) {
        #pragma unroll
        for (int l = 0; l < 2; ++l)
            __builtin_amdgcn_global_load_lds(
                GAS(Bp + (size_t)(h * 128 + l * 64 + sr) * K + t * 64 + su * 8),
                LAS(&Bs[t & 1][h][l * 4096 + tid * 8]), 16, 0, 0);
    };
    auto rdA = [&](int b, int q, int f, int kk) {   // wave wr reads only A-half wr
        int row = q * 32 + f * 16 + lr;
        return *(const bf16x8*)&As[b][wr][row * 64 + (((kk * 4 + lu) ^ (row & 7)) << 3)];
    };
    auto rdB = [&](int b, int n, int kk) {          // wave wc reads only B-half wc>>1
        int row = (wc & 1) * 64 + n * 16 + lr;
        return *(const bf16x8*)&Bs[b][wc >> 1][row * 64 + (((kk * 4 + lu) ^ (row & 7)) << 3)];
    };

#define BAR() asm volatile("s_barrier" ::: "memory")
#define VM4() asm volatile("s_waitcnt vmcnt(4)" ::: "memory")
#define VM0() asm volatile("s_waitcnt vmcnt(0)" ::: "memory")
#define CLUSTER(Q)                                                                                          \
    __builtin_amdgcn_s_setprio(1);                                                                          \
    _Pragma("unroll") for (int n = 0; n < 4; ++n)                                                           \
        acc[2*(Q)+0][n] = __builtin_amdgcn_mfma_f32_16x16x32_bf16(af[0][0], bq[n][0], acc[2*(Q)+0][n], 0, 0, 0); \
    _Pragma("unroll") for (int n = 0; n < 4; ++n)                                                           \
        acc[2*(Q)+1][n] = __builtin_amdgcn_mfma_f32_16x16x32_bf16(af[1][0], bq[n][0], acc[2*(Q)+1][n], 0, 0, 0); \
    _Pragma("unroll") for (int n = 0; n < 4; ++n)                                                           \
        acc[2*(Q)+0][n] = __builtin_amdgcn_mfma_f32_16x16x32_bf16(af[0][1], bq[n][1], acc[2*(Q)+0][n], 0, 0, 0); \
    _Pragma("unroll") for (int n = 0; n < 4; ++n)                                                           \
        acc[2*(Q)+1][n] = __builtin_amdgcn_mfma_f32_16x16x32_bf16(af[1][1], bq[n][1], acc[2*(Q)+1][n], 0, 0, 0); \
    __builtin_amdgcn_s_setprio(0);
// single-barrier phase (no VM): reads -> stage -> MFMA -> barrier
#define PH(B_, Q_, STAGE)                                                       \
    {   bf16x8 af[2][2];                                                        \
        _Pragma("unroll") for (int f = 0; f < 2; ++f) {                         \
            af[f][0] = rdA(B_, Q_, f, 0); af[f][1] = rdA(B_, Q_, f, 1); }       \
        STAGE                                                                   \
        CLUSTER(Q_)                                                             \
        BAR(); }
// VM phase: reads -> stage -> VM -> barrier (collective landing) -> MFMA -> barrier
#define PHV(B_, Q_, STAGE, VMSTMT)                                              \
    {   bf16x8 af[2][2];                                                        \
        _Pragma("unroll") for (int f = 0; f < 2; ++f) {                         \
            af[f][0] = rdA(B_, Q_, f, 0); af[f][1] = rdA(B_, Q_, f, 1); }       \
        STAGE                                                                   \
        VMSTMT                                                                  \
        BAR();                                                                  \
        CLUSTER(Q_)                                                             \
        BAR(); }

    // prologue: B(0),A(0),B(1) = 12 loads; VM4 retires tile-0's 8, leaves B(1)'s 4
    stageBh(0, 0); stageBh(0, 1);
    stageAh(0, 0); stageAh(0, 1);
    stageBh(1, 0); stageBh(1, 1);
    VM4();
    BAR();

    for (int i = 0; i < NI; ++i) {
        const int t0 = 2 * i, t1 = 2 * i + 1;
        const bool full = (i + 1 < NI);
        // ---- tile t0 (buf 0) ----
        #pragma unroll
        for (int n = 0; n < 4; ++n) { bq[n][0] = rdB(0, n, 0); bq[n][1] = rdB(0, n, 1); }
        PH(0, 0, { stageAh(t1, 0); stageAh(t1, 1); })
        PH(0, 1, { if (full) stageBh(t0 + 2, 0); })
        PH(0, 2, { if (full) stageBh(t0 + 2, 1); })
        PHV(0, 3, { }, { if (full) { VM4(); } else { VM0(); } })
        // ---- tile t1 (buf 1) ----
        #pragma unroll
        for (int n = 0; n < 4; ++n) { bq[n][0] = rdB(1, n, 0); bq[n][1] = rdB(1, n, 1); }
        PH(1, 0, { if (full) stageAh(t0 + 2, 0); })
        PH(1, 1, { if (full) stageAh(t0 + 2, 1); })
        PH(1, 2, { if (full) stageBh(t1 + 2, 0); })
        PHV(1, 3, { if (full) stageBh(t1 + 2, 1); }, { if (full) { VM4(); } else { VM0(); } })
    }
#undef PHV
#undef PH
#undef CLUSTER
#undef VM0
#undef VM4
#undef BAR

    // epilogue: C-write with bias, col-bounded
    const int r4 = lu * 4;
    #pragma unroll
    for (int m = 0; m < 8; ++m) {
        #pragma unroll
        for (int n = 0; n < 4; ++n) {
            int col = bn * 256 + wc * 64 + n * 16 + lr;
            if (col < ncols) {
                float bv_ = bias[col];
                #pragma unroll
                for (int r = 0; r < 4; ++r) {
                    int row = bm * 256 + wr * 128 + m * 16 + r4 + r;
                    out[(size_t)row * ldc + col] = acc[m][n][r] + bv_;
                }
            }
        }
    }
}

// ---------------- causal softmax: float4 loads, __expf, zero-fill to 128-boundary ----------------
__global__ __launch_bounds__(256) void k_softmax(const float* __restrict__ att,
    __hip_bfloat16* __restrict__ P, int T)
{
    int t = blockIdx.x, b = blockIdx.y;
    const float* row = att + ((size_t)b * T + t) * T;
    __hip_bfloat16* prow = P + ((size_t)b * T + t) * T;
    const int n = t + 1;
    const int nz = ((t >> 7) + 1) << 7;     // PV (truncated) reads only cols < nz
    __shared__ float red[256];
    float4 v[2];
    float mx = -1e30f;
    #pragma unroll
    for (int j = 0; j < 2; ++j) {
        int e = (threadIdx.x + j * 256) * 4;
        v[j] = *(const float4*)(row + e);
        #pragma unroll
        for (int k = 0; k < 4; ++k)
            if (e + k < n) mx = fmaxf(mx, ((const float*)&v[j])[k]);
    }
    red[threadIdx.x] = mx; __syncthreads();
    for (int o = 128; o > 0; o >>= 1) {
        if (threadIdx.x < o) red[threadIdx.x] = fmaxf(red[threadIdx.x], red[threadIdx.x + o]);
        __syncthreads();
    }
    mx = red[0]; __syncthreads();
    float ev[8];
    float sum = 0.f;
    #pragma unroll
    for (int j = 0; j < 2; ++j) {
        int e = (threadIdx.x + j * 256) * 4;
        #pragma unroll
        for (int k = 0; k < 4; ++k) {
            float x = ((const float*)&v[j])[k];
            float ex = (e + k < n) ? __expf(x - mx) : 0.f;
            ev[j * 4 + k] = ex;
            sum += ex;
        }
    }
    red[threadIdx.x] = sum; __syncthreads();
    for (int o = 128; o > 0; o >>= 1) {
        if (threadIdx.x < o) red[threadIdx.x] += red[threadIdx.x + o];
        __syncthreads();
    }
    float inv = 1.f / red[0];
    #pragma unroll
    for (int j = 0; j < 2; ++j) {
        int e = (threadIdx.x + j * 256) * 4;
        #pragma unroll
        for (int k = 0; k < 4; ++k)
            if (e + k < nz) prow[e + k] = __float2bfloat16(ev[j * 4 + k] * inv);
    }
}

// ---------------- LayerNorm (eps 1e-5) fp32 -> bf16 ----------------
__global__ __launch_bounds__(256) void k_layernorm(const float* __restrict__ y,
    const float* __restrict__ g, const float* __restrict__ b,
    __hip_bfloat16* __restrict__ yn)
{
    int row = blockIdx.x;
    const float* yr = y + (size_t)row * NE;
    float s = 0.f, s2 = 0.f;
    for (int c = threadIdx.x; c < NE; c += 256) { float v = yr[c]; s += v; s2 += v * v; }
    __shared__ float r1[256], r2[256];
    r1[threadIdx.x] = s; r2[threadIdx.x] = s2; __syncthreads();
    for (int o = 128; o > 0; o >>= 1) {
        if (threadIdx.x < o) { r1[threadIdx.x] += r1[threadIdx.x + o]; r2[threadIdx.x] += r2[threadIdx.x + o]; }
        __syncthreads();
    }
    float mu = r1[0] / NE;
    float var = r2[0] / NE - mu * mu;
    float rs = rsqrtf(var + 1e-5f);
    __hip_bfloat16* o = yn + (size_t)row * NE;
    for (int c = threadIdx.x; c < NE; c += 256)
        o[c] = __float2bfloat16((yr[c] - mu) * rs * g[c] + b[c]);
}

extern "C" void kernel_launch(void* const* d_in, const int* in_sizes, int n_in,
                              void* d_out, int out_size, void* d_ws, size_t ws_size,
                              hipStream_t stream)
{
    const int*   idx  = (const int*)  d_in[0];
    const float* tok  = (const float*)d_in[1];
    const float* pos  = (const float*)d_in[2];
    const float* Wq   = (const float*)d_in[3];
    const float* bq   = (const float*)d_in[4];
    const float* Wk   = (const float*)d_in[5];
    const float* bk   = (const float*)d_in[6];
    const float* Wv   = (const float*)d_in[7];
    const float* bv   = (const float*)d_in[8];
    const float* ln_g = (const float*)d_in[9];
    const float* ln_b = (const float*)d_in[10];
    const float* Wh   = (const float*)d_in[11];
    const float* bh   = (const float*)d_in[12];
    float* out = (float*)d_out;

    const int B = 4, T = 2048, C = 768, V = 50257, Vp = 50432;  // Vp = 197*256

    char* p = (char*)d_ws;
    auto take = [&](size_t bytes) { char* r = p; p += (bytes + 255) & ~(size_t)255; return r; };
    __hip_bfloat16* xb    = (__hip_bfloat16*)take((size_t)B * T * C * 2);
    __hip_bfloat16* wqkvT = (__hip_bfloat16*)take((size_t)3 * C * C * 2);
    float*          bqkv  = (float*)take((size_t)3 * C * 4);
    __hip_bfloat16* qb    = (__hip_bfloat16*)take((size_t)B * T * C * 2);
    __hip_bfloat16* kb    = (__hip_bfloat16*)take((size_t)B * T * C * 2);
    __hip_bfloat16* vb    = (__hip_bfloat16*)take((size_t)B * T * C * 2);
    __hip_bfloat16* vT    = (__hip_bfloat16*)take((size_t)B * T * C * 2);
    float*          att   = (float*)take((size_t)B * T * T * 4);
    __hip_bfloat16* P     = (__hip_bfloat16*)take((size_t)B * T * T * 2);
    float*          y     = (float*)take((size_t)B * T * C * 4);
    __hip_bfloat16* yn    = (__hip_bfloat16*)take((size_t)B * T * C * 2);
    // Wh^T (77.4 MB, Vp rows) reuses the att+P region (100.6 MB) — dead once y exists.
    __hip_bfloat16* whT   = (__hip_bfloat16*)att;

    float scale = 1.0f / sqrtf((float)C);

    k_embed<<<dim3(B * T), 256, 0, stream>>>(idx, tok, pos, xb);
    k_transpose_f32_bf16<<<dim3(24, 24), 256, 0, stream>>>(Wq, wqkvT,             C, C, C);
    k_transpose_f32_bf16<<<dim3(24, 24), 256, 0, stream>>>(Wk, wqkvT + C * C,     C, C, C);
    k_transpose_f32_bf16<<<dim3(24, 24), 256, 0, stream>>>(Wv, wqkvT + 2 * C * C, C, C, C);
    k_pack_bias<<<dim3(9), 256, 0, stream>>>(bq, bk, bv, bqkv);

    // qkv: [8192,768] x [2304,768]^T
    k_gemm<0><<<dim3(18, 64, 1), 256, 0, stream>>>(xb, wqkvT, C, C, C, 0, 0, 0,
        nullptr, 0, 0, bqkv, 1.f, qb, kb, vb);

    k_transpose_bf16<<<dim3(24, 64, B), 256, 0, stream>>>(vb, vT, T, C);

    // att = q k^T / sqrt(C): per batch [2048,768] x [2048,768]^T (causal block skip)
    k_gemm<1><<<dim3(16, 16, B), 256, 0, stream>>>(qb, kb, C, C, C,
        (size_t)T * C, (size_t)T * C, (size_t)T * T, att, T, 0, nullptr, scale,
        nullptr, nullptr, nullptr);

    k_softmax<<<dim3(T, B), 256, 0, stream>>>(att, P, T);

    // y = P v: per batch [2048,2048] x [768,2048]^T, K truncated causally, longest-first
    k_gemm<2><<<dim3(6, 16, B), 256, 0, stream>>>(P, vT, T, T, T,
        (size_t)T * T, (size_t)C * T, (size_t)T * C, y, C, 0, nullptr, 1.f,
        nullptr, nullptr, nullptr);

    // Wh^T after PV so it can overwrite att/P scratch
    k_transpose_f32_bf16<<<dim3(Vp / 32, 24), 256, 0, stream>>>(Wh, whT, C, V, Vp);

    k_layernorm<<<dim3(B * T), 256, 0, stream>>>(y, ln_g, ln_b, yn);

    // logits: [8192,768] x [50432,768]^T -> fp32 d_out; single-barrier 8-phase + XCD swizzle
    k_gemm_head<<<dim3(Vp / 256, 32), 512, 0, stream>>>(yn, whT, out, bh, V, V);
}

// Round 14
// 1188.566 us; speedup vs baseline: 1.3830x; 1.0202x over previous
//
#include <hip/hip_runtime.h>
#include <hip/hip_bf16.h>
#include <math.h>

typedef __bf16 bf16x8 __attribute__((ext_vector_type(8)));
typedef float  f32x4  __attribute__((ext_vector_type(4)));

#define GAS(p) ((const __attribute__((address_space(1))) void*)(p))
#define LAS(p) ((__attribute__((address_space(3))) void*)(p))

static constexpr int NE = 768;

// ---------------- embed: x = tok_emb[idx] + pos_emb, -> bf16 ----------------
__global__ __launch_bounds__(256) void k_embed(const int* __restrict__ idx,
    const float* __restrict__ tok, const float* __restrict__ pos,
    __hip_bfloat16* __restrict__ xb)
{
    int bt = blockIdx.x;            // 0..8191
    int t  = bt & 2047;
    int token = idx[bt];
    const float* te = tok + (size_t)token * NE;
    const float* pe = pos + (size_t)t * NE;
    __hip_bfloat16* o = xb + (size_t)bt * NE;
    for (int c = threadIdx.x; c < NE; c += 256)
        o[c] = __float2bfloat16(te[c] + pe[c]);
}

// ------------- transpose fp32 [R][C] -> bf16 [outRows][R] (zero-pad), small weights -------------
__global__ __launch_bounds__(256) void k_transpose_f32_bf16(
    const float* __restrict__ in, __hip_bfloat16* __restrict__ out,
    int R, int C, int outRows)
{
    __shared__ float tile[32][33];
    int c0 = blockIdx.x * 32, r0 = blockIdx.y * 32;
    int tx = threadIdx.x & 31, ty = threadIdx.x >> 5;
    #pragma unroll
    for (int i = 0; i < 32; i += 8) {
        int r = r0 + ty + i, c = c0 + tx;
        tile[ty + i][tx] = (r < R && c < C) ? in[(size_t)r * C + c] : 0.f;
    }
    __syncthreads();
    #pragma unroll
    for (int i = 0; i < 32; i += 8) {
        int oc = c0 + ty + i, orr = r0 + tx;
        if (oc < outRows && orr < R)
            out[(size_t)oc * R + orr] = __float2bfloat16(tile[tx][ty + i]);
    }
}

// ------------- Wh transpose: fp32 [768][50257] -> bf16 [50432][768], vectorized -------------
// 64x64 tile; float4 reads (guarded scalar at V boundary), bf16x8 writes.
__global__ __launch_bounds__(256) void k_transpose_wh(
    const float* __restrict__ in, __hip_bfloat16* __restrict__ out,
    int R /*768*/, int C /*50257*/)
{
    __shared__ float tile[64][65];
    const int n0 = blockIdx.x * 64, k0 = blockIdx.y * 64;
    const int t = threadIdx.x;
    if (n0 + 64 <= C) {              // fast path: full float4 tile
        #pragma unroll
        for (int pass = 0; pass < 4; ++pass) {
            int idx = pass * 256 + t;
            int kr = idx >> 4, nc4 = (idx & 15) * 4;
            float4 v = *(const float4*)(in + (size_t)(k0 + kr) * C + n0 + nc4);
            tile[kr][nc4] = v.x; tile[kr][nc4 + 1] = v.y;
            tile[kr][nc4 + 2] = v.z; tile[kr][nc4 + 3] = v.w;
        }
    } else {                         // boundary: guarded scalar
        #pragma unroll
        for (int pass = 0; pass < 16; ++pass) {
            int idx = pass * 256 + t;
            int kr = idx >> 6, nc = idx & 63;
            int c = n0 + nc;
            tile[kr][nc] = (c < C) ? in[(size_t)(k0 + kr) * C + c] : 0.f;
        }
    }
    __syncthreads();
    #pragma unroll
    for (int pass = 0; pass < 2; ++pass) {
        int nr = pass * 32 + (t >> 3);
        int kc = (t & 7) * 8;
        bf16x8 v;
        #pragma unroll
        for (int j = 0; j < 8; ++j) {
            __hip_bfloat16 h = __float2bfloat16(tile[kc + j][nr]);
            v[j] = *reinterpret_cast<__bf16*>(&h);
        }
        *(bf16x8*)(out + (size_t)(n0 + nr) * R + k0 + kc) = v;
    }
}

// ------------- batched bf16 transpose: in [z][R][C] -> out [z][C][R] -------------
__global__ __launch_bounds__(256) void k_transpose_bf16(
    const __hip_bfloat16* __restrict__ in, __hip_bfloat16* __restrict__ out,
    int R, int C)
{
    __shared__ __hip_bfloat16 tile[32][33];
    size_t boff = (size_t)blockIdx.z * R * C;
    int c0 = blockIdx.x * 32, r0 = blockIdx.y * 32;
    int tx = threadIdx.x & 31, ty = threadIdx.x >> 5;
    #pragma unroll
    for (int i = 0; i < 32; i += 8)
        tile[ty + i][tx] = in[boff + (size_t)(r0 + ty + i) * C + (c0 + tx)];
    __syncthreads();
    #pragma unroll
    for (int i = 0; i < 32; i += 8)
        out[boff + (size_t)(c0 + ty + i) * R + (r0 + tx)] = tile[tx][ty + i];
}

__global__ __launch_bounds__(256) void k_pack_bias(const float* __restrict__ bq,
    const float* __restrict__ bk, const float* __restrict__ bv, float* __restrict__ o)
{
    int i = blockIdx.x * 256 + threadIdx.x;
    if (i < 768) o[i] = bq[i];
    else if (i < 1536) o[i] = bk[i - 768];
    else if (i < 2304) o[i] = bv[i - 1536];
}

// ---------------- m97-style 128x128 bf16 MFMA GEMM (PV only) ----------------
// MODE 2: PV (fp32 out, K truncated to (bm+1)*128; bm reversed so longest blocks start first)
template<int MODE>
__global__ __launch_bounds__(256) void k_gemm(
    const __hip_bfloat16* __restrict__ A, const __hip_bfloat16* __restrict__ Bt,
    int K, int lda, int ldb,
    size_t strideA, size_t strideB, size_t strideC,
    float* __restrict__ outf, int ldc, int ncols,
    const float* __restrict__ bias, float scale,
    __hip_bfloat16* __restrict__ oq, __hip_bfloat16* __restrict__ ok,
    __hip_bfloat16* __restrict__ ov)
{
    int bn = blockIdx.x, bm = blockIdx.y, bz = blockIdx.z;
    if constexpr (MODE == 2) bm = (int)gridDim.y - 1 - bm;   // longest-first dispatch
    __shared__ __align__(16) __hip_bfloat16 As[128 * 32];
    __shared__ __align__(16) __hip_bfloat16 Bs[128 * 32];
    const __hip_bfloat16* Ab = A  + bz * strideA + (size_t)bm * 128 * lda;
    const __hip_bfloat16* Bb = Bt + bz * strideB + (size_t)bn * 128 * ldb;
    int tid = threadIdx.x, w = tid >> 6, lane = tid & 63;
    int wr = w >> 1, wc = w & 1;
    f32x4 acc[4][4] = {};
    int sr = tid >> 2, sc = (tid & 3) * 8;
    int lr = lane & 15, lk = (lane >> 4) * 8;

    const int kend = (MODE == 2) ? (bm + 1) * 128 : K;   // causal K-truncation for PV

    for (int k0 = 0; k0 < kend; k0 += 32) {
        __syncthreads();
        #pragma unroll
        for (int i = 0; i < 2; ++i) {
            __builtin_amdgcn_global_load_lds(GAS(Ab + (size_t)(i * 64 + sr) * lda + k0 + sc),
                                             LAS((char*)As + i * 4096 + w * 1024), 16, 0, 0);
            __builtin_amdgcn_global_load_lds(GAS(Bb + (size_t)(i * 64 + sr) * ldb + k0 + sc),
                                             LAS((char*)Bs + i * 4096 + w * 1024), 16, 0, 0);
        }
        __syncthreads();
        bf16x8 af[4], bfv[4];
        #pragma unroll
        for (int mi = 0; mi < 4; ++mi)
            af[mi] = *(const bf16x8*)(As + (wr * 64 + mi * 16 + lr) * 32 + lk);
        #pragma unroll
        for (int ni = 0; ni < 4; ++ni)
            bfv[ni] = *(const bf16x8*)(Bs + (wc * 64 + ni * 16 + lr) * 32 + lk);
        #pragma unroll
        for (int mi = 0; mi < 4; ++mi)
            #pragma unroll
            for (int ni = 0; ni < 4; ++ni)
                acc[mi][ni] = __builtin_amdgcn_mfma_f32_16x16x32_bf16(af[mi], bfv[ni], acc[mi][ni], 0, 0, 0);
    }

    int r4 = (lane >> 4) * 4;
    #pragma unroll
    for (int mi = 0; mi < 4; ++mi) {
        #pragma unroll
        for (int ni = 0; ni < 4; ++ni) {
            #pragma unroll
            for (int r = 0; r < 4; ++r) {
                int row = bm * 128 + wr * 64 + mi * 16 + r4 + r;
                int col = bn * 128 + wc * 64 + ni * 16 + lr;
                outf[bz * strideC + (size_t)row * ldc + col] = acc[mi][ni][r];
            }
        }
    }
}

// ================= unified 256x256 8-phase GEMM (R13 schedule, verified) =================
// MODE 0: qkv (bf16 out split q/k/v, +bias)  grid (9, 32, 1)
// MODE 1: att (fp32 out * scale, batched, causal 256-tile skip)  grid (8, 8, B)
// MODE 3: head (fp32 out + bias, col-bounded)  grid (197, 32, 1)
// Single-barrier phases except VM phases (ph3/ph7) which keep the mid-barrier to make
// per-wave vmcnt(4) a collective landing guarantee. Ledger identical to R13 (verified).
template<int MODE>
__global__ __launch_bounds__(512, 2) void k_gemm8(
    const __hip_bfloat16* __restrict__ A, const __hip_bfloat16* __restrict__ Bt,
    float* __restrict__ outf, int ldc, int ncols,
    const float* __restrict__ bias, float scale,
    __hip_bfloat16* __restrict__ oq, __hip_bfloat16* __restrict__ ok,
    __hip_bfloat16* __restrict__ ov,
    size_t strideA, size_t strideB, size_t strideC)
{
    constexpr int K = 768, NT = K / 64, NI = NT / 2;    // 12 tiles, 6 iters
    __shared__ __align__(16) __hip_bfloat16 As[2][2][128 * 64];  // [buf][half]
    __shared__ __align__(16) __hip_bfloat16 Bs[2][2][128 * 64];

    // bijective XCD remap of fast axis
    const int Nx = (int)gridDim.x;
    const int qq = Nx >> 3, rr = Nx & 7;
    const int xcd = (int)blockIdx.x & 7, xidx = (int)blockIdx.x >> 3;
    const int bn = (xcd < rr ? xcd * (qq + 1) : rr * (qq + 1) + (xcd - rr) * qq) + xidx;
    const int bm = blockIdx.y, bz = blockIdx.z;
    if (MODE == 1 && bn > bm) return;   // fully masked causal 256-tile
    const int tid = threadIdx.x;
    const int w = tid >> 6, lane = tid & 63;
    const int wr = w >> 2, wc = w & 3;      // wave = (M-half wr, N-quarter wc)
    const int lr = lane & 15, lu = lane >> 4;

    const int sr = tid >> 3;                // staging row within 64-row chunk
    const int su = (tid & 7) ^ (sr & 7);    // pre-swizzled source 16B unit
    const __hip_bfloat16* Ap = A  + bz * strideA + (size_t)(bm * 256) * K;
    const __hip_bfloat16* Bp = Bt + bz * strideB + (size_t)(bn * 256) * K;

    f32x4 acc[8][4] = {};
    bf16x8 bq[4][2];

    auto stageAh = [&](int t, int h) {      // A half h (128 rows x 64) -> buf t&1
        #pragma unroll
        for (int l = 0; l < 2; ++l)
            __builtin_amdgcn_global_load_lds(
                GAS(Ap + (size_t)(h * 128 + l * 64 + sr) * K + t * 64 + su * 8),
                LAS(&As[t & 1][h][l * 4096 + tid * 8]), 16, 0, 0);
    };
    auto stageBh = [&](int t, int h) {
        #pragma unroll
        for (int l = 0; l < 2; ++l)
            __builtin_amdgcn_global_load_lds(
                GAS(Bp + (size_t)(h * 128 + l * 64 + sr) * K + t * 64 + su * 8),
                LAS(&Bs[t & 1][h][l * 4096 + tid * 8]), 16, 0, 0);
    };
    auto rdA = [&](int b, int q, int f, int kk) {   // wave wr reads only A-half wr
        int row = q * 32 + f * 16 + lr;
        return *(const bf16x8*)&As[b][wr][row * 64 + (((kk * 4 + lu) ^ (row & 7)) << 3)];
    };
    auto rdB = [&](int b, int n, int kk) {          // wave wc reads only B-half wc>>1
        int row = (wc & 1) * 64 + n * 16 + lr;
        return *(const bf16x8*)&Bs[b][wc >> 1][row * 64 + (((kk * 4 + lu) ^ (row & 7)) << 3)];
    };

#define BAR() asm volatile("s_barrier" ::: "memory")
#define VM4() asm volatile("s_waitcnt vmcnt(4)" ::: "memory")
#define VM0() asm volatile("s_waitcnt vmcnt(0)" ::: "memory")
#define CLUSTER(Q)                                                                                          \
    __builtin_amdgcn_s_setprio(1);                                                                          \
    _Pragma("unroll") for (int n = 0; n < 4; ++n)                                                           \
        acc[2*(Q)+0][n] = __builtin_amdgcn_mfma_f32_16x16x32_bf16(af[0][0], bq[n][0], acc[2*(Q)+0][n], 0, 0, 0); \
    _Pragma("unroll") for (int n = 0; n < 4; ++n)                                                           \
        acc[2*(Q)+1][n] = __builtin_amdgcn_mfma_f32_16x16x32_bf16(af[1][0], bq[n][0], acc[2*(Q)+1][n], 0, 0, 0); \
    _Pragma("unroll") for (int n = 0; n < 4; ++n)                                                           \
        acc[2*(Q)+0][n] = __builtin_amdgcn_mfma_f32_16x16x32_bf16(af[0][1], bq[n][1], acc[2*(Q)+0][n], 0, 0, 0); \
    _Pragma("unroll") for (int n = 0; n < 4; ++n)                                                           \
        acc[2*(Q)+1][n] = __builtin_amdgcn_mfma_f32_16x16x32_bf16(af[1][1], bq[n][1], acc[2*(Q)+1][n], 0, 0, 0); \
    __builtin_amdgcn_s_setprio(0);
#define PH(B_, Q_, STAGE)                                                       \
    {   bf16x8 af[2][2];                                                        \
        _Pragma("unroll") for (int f = 0; f < 2; ++f) {                         \
            af[f][0] = rdA(B_, Q_, f, 0); af[f][1] = rdA(B_, Q_, f, 1); }       \
        STAGE                                                                   \
        CLUSTER(Q_)                                                             \
        BAR(); }
#define PHV(B_, Q_, STAGE, VMSTMT)                                              \
    {   bf16x8 af[2][2];                                                        \
        _Pragma("unroll") for (int f = 0; f < 2; ++f) {                         \
            af[f][0] = rdA(B_, Q_, f, 0); af[f][1] = rdA(B_, Q_, f, 1); }       \
        STAGE                                                                   \
        VMSTMT                                                                  \
        BAR();                                                                  \
        CLUSTER(Q_)                                                             \
        BAR(); }

    // prologue: B(0),A(0),B(1) = 12 loads; VM4 retires tile-0's 8, leaves B(1)'s 4
    stageBh(0, 0); stageBh(0, 1);
    stageAh(0, 0); stageAh(0, 1);
    stageBh(1, 0); stageBh(1, 1);
    VM4();
    BAR();

    for (int i = 0; i < NI; ++i) {
        const int t0 = 2 * i, t1 = 2 * i + 1;
        const bool full = (i + 1 < NI);
        // ---- tile t0 (buf 0) ----
        #pragma unroll
        for (int n = 0; n < 4; ++n) { bq[n][0] = rdB(0, n, 0); bq[n][1] = rdB(0, n, 1); }
        PH(0, 0, { stageAh(t1, 0); stageAh(t1, 1); })
        PH(0, 1, { if (full) stageBh(t0 + 2, 0); })
        PH(0, 2, { if (full) stageBh(t0 + 2, 1); })
        PHV(0, 3, { }, { if (full) { VM4(); } else { VM0(); } })
        // ---- tile t1 (buf 1) ----
        #pragma unroll
        for (int n = 0; n < 4; ++n) { bq[n][0] = rdB(1, n, 0); bq[n][1] = rdB(1, n, 1); }
        PH(1, 0, { if (full) stageAh(t0 + 2, 0); })
        PH(1, 1, { if (full) stageAh(t0 + 2, 1); })
        PH(1, 2, { if (full) stageBh(t1 + 2, 0); })
        PHV(1, 3, { if (full) stageBh(t1 + 2, 1); }, { if (full) { VM4(); } else { VM0(); } })
    }
#undef PHV
#undef PH
#undef CLUSTER
#undef VM0
#undef VM4
#undef BAR

    // epilogue (mapping verified): row = bm*256 + wr*128 + m*16 + lu*4 + r, col = bn*256 + wc*64 + n*16 + lr
    const int r4 = lu * 4;
    #pragma unroll
    for (int m = 0; m < 8; ++m) {
        #pragma unroll
        for (int n = 0; n < 4; ++n) {
            int col = bn * 256 + wc * 64 + n * 16 + lr;
            if constexpr (MODE == 0) {
                float bv_ = bias[col];
                #pragma unroll
                for (int r = 0; r < 4; ++r) {
                    int row = bm * 256 + wr * 128 + m * 16 + r4 + r;
                    __hip_bfloat16 h = __float2bfloat16(acc[m][n][r] + bv_);
                    if (col < 768)       oq[(size_t)row * 768 + col]          = h;
                    else if (col < 1536) ok[(size_t)row * 768 + (col - 768)]  = h;
                    else                 ov[(size_t)row * 768 + (col - 1536)] = h;
                }
            } else if constexpr (MODE == 1) {
                #pragma unroll
                for (int r = 0; r < 4; ++r) {
                    int row = bm * 256 + wr * 128 + m * 16 + r4 + r;
                    outf[bz * strideC + (size_t)row * ldc + col] = acc[m][n][r] * scale;
                }
            } else {
                if (col < ncols) {
                    float bv_ = bias[col];
                    #pragma unroll
                    for (int r = 0; r < 4; ++r) {
                        int row = bm * 256 + wr * 128 + m * 16 + r4 + r;
                        outf[(size_t)row * ldc + col] = acc[m][n][r] + bv_;
                    }
                }
            }
        }
    }
}

// ---------------- causal softmax: float4 loads, __expf, zero-fill to 128-boundary ----------------
__global__ __launch_bounds__(256) void k_softmax(const float* __restrict__ att,
    __hip_bfloat16* __restrict__ P, int T)
{
    int t = blockIdx.x, b = blockIdx.y;
    const float* row = att + ((size_t)b * T + t) * T;
    __hip_bfloat16* prow = P + ((size_t)b * T + t) * T;
    const int n = t + 1;
    const int nz = ((t >> 7) + 1) << 7;     // PV (truncated) reads only cols < nz
    __shared__ float red[256];
    float4 v[2];
    float mx = -1e30f;
    #pragma unroll
    for (int j = 0; j < 2; ++j) {
        int e = (threadIdx.x + j * 256) * 4;
        v[j] = *(const float4*)(row + e);
        #pragma unroll
        for (int k = 0; k < 4; ++k)
            if (e + k < n) mx = fmaxf(mx, ((const float*)&v[j])[k]);
    }
    red[threadIdx.x] = mx; __syncthreads();
    for (int o = 128; o > 0; o >>= 1) {
        if (threadIdx.x < o) red[threadIdx.x] = fmaxf(red[threadIdx.x], red[threadIdx.x + o]);
        __syncthreads();
    }
    mx = red[0]; __syncthreads();
    float ev[8];
    float sum = 0.f;
    #pragma unroll
    for (int j = 0; j < 2; ++j) {
        int e = (threadIdx.x + j * 256) * 4;
        #pragma unroll
        for (int k = 0; k < 4; ++k) {
            float x = ((const float*)&v[j])[k];
            float ex = (e + k < n) ? __expf(x - mx) : 0.f;
            ev[j * 4 + k] = ex;
            sum += ex;
        }
    }
    red[threadIdx.x] = sum; __syncthreads();
    for (int o = 128; o > 0; o >>= 1) {
        if (threadIdx.x < o) red[threadIdx.x] += red[threadIdx.x + o];
        __syncthreads();
    }
    float inv = 1.f / red[0];
    #pragma unroll
    for (int j = 0; j < 2; ++j) {
        int e = (threadIdx.x + j * 256) * 4;
        #pragma unroll
        for (int k = 0; k < 4; ++k)
            if (e + k < nz) prow[e + k] = __float2bfloat16(ev[j * 4 + k] * inv);
    }
}

// ---------------- LayerNorm (eps 1e-5) fp32 -> bf16 ----------------
__global__ __launch_bounds__(256) void k_layernorm(const float* __restrict__ y,
    const float* __restrict__ g, const float* __restrict__ b,
    __hip_bfloat16* __restrict__ yn)
{
    int row = blockIdx.x;
    const float* yr = y + (size_t)row * NE;
    float s = 0.f, s2 = 0.f;
    for (int c = threadIdx.x; c < NE; c += 256) { float v = yr[c]; s += v; s2 += v * v; }
    __shared__ float r1[256], r2[256];
    r1[threadIdx.x] = s; r2[threadIdx.x] = s2; __syncthreads();
    for (int o = 128; o > 0; o >>= 1) {
        if (threadIdx.x < o) { r1[threadIdx.x] += r1[threadIdx.x + o]; r2[threadIdx.x] += r2[threadIdx.x + o]; }
        __syncthreads();
    }
    float mu = r1[0] / NE;
    float var = r2[0] / NE - mu * mu;
    float rs = rsqrtf(var + 1e-5f);
    __hip_bfloat16* o = yn + (size_t)row * NE;
    for (int c = threadIdx.x; c < NE; c += 256)
        o[c] = __float2bfloat16((yr[c] - mu) * rs * g[c] + b[c]);
}

extern "C" void kernel_launch(void* const* d_in, const int* in_sizes, int n_in,
                              void* d_out, int out_size, void* d_ws, size_t ws_size,
                              hipStream_t stream)
{
    const int*   idx  = (const int*)  d_in[0];
    const float* tok  = (const float*)d_in[1];
    const float* pos  = (const float*)d_in[2];
    const float* Wq   = (const float*)d_in[3];
    const float* bq   = (const float*)d_in[4];
    const float* Wk   = (const float*)d_in[5];
    const float* bk   = (const float*)d_in[6];
    const float* Wv   = (const float*)d_in[7];
    const float* bv   = (const float*)d_in[8];
    const float* ln_g = (const float*)d_in[9];
    const float* ln_b = (const float*)d_in[10];
    const float* Wh   = (const float*)d_in[11];
    const float* bh   = (const float*)d_in[12];
    float* out = (float*)d_out;

    const int B = 4, T = 2048, C = 768, V = 50257, Vp = 50432;  // Vp = 197*256 = 788*64

    char* p = (char*)d_ws;
    auto take = [&](size_t bytes) { char* r = p; p += (bytes + 255) & ~(size_t)255; return r; };
    __hip_bfloat16* xb    = (__hip_bfloat16*)take((size_t)B * T * C * 2);
    __hip_bfloat16* wqkvT = (__hip_bfloat16*)take((size_t)3 * C * C * 2);
    float*          bqkv  = (float*)take((size_t)3 * C * 4);
    __hip_bfloat16* qb    = (__hip_bfloat16*)take((size_t)B * T * C * 2);
    __hip_bfloat16* kb    = (__hip_bfloat16*)take((size_t)B * T * C * 2);
    __hip_bfloat16* vb    = (__hip_bfloat16*)take((size_t)B * T * C * 2);
    __hip_bfloat16* vT    = (__hip_bfloat16*)take((size_t)B * T * C * 2);
    float*          att   = (float*)take((size_t)B * T * T * 4);
    __hip_bfloat16* P     = (__hip_bfloat16*)take((size_t)B * T * T * 2);
    float*          y     = (float*)take((size_t)B * T * C * 4);
    __hip_bfloat16* yn    = (__hip_bfloat16*)take((size_t)B * T * C * 2);
    // Wh^T (77.4 MB, Vp rows) reuses the att+P region (100.6 MB) — dead once y exists.
    __hip_bfloat16* whT   = (__hip_bfloat16*)att;

    float scale = 1.0f / sqrtf((float)C);

    k_embed<<<dim3(B * T), 256, 0, stream>>>(idx, tok, pos, xb);
    k_transpose_f32_bf16<<<dim3(24, 24), 256, 0, stream>>>(Wq, wqkvT,             C, C, C);
    k_transpose_f32_bf16<<<dim3(24, 24), 256, 0, stream>>>(Wk, wqkvT + C * C,     C, C, C);
    k_transpose_f32_bf16<<<dim3(24, 24), 256, 0, stream>>>(Wv, wqkvT + 2 * C * C, C, C, C);
    k_pack_bias<<<dim3(9), 256, 0, stream>>>(bq, bk, bv, bqkv);

    // qkv: [8192,768] x [2304,768]^T, 8-phase kernel
    k_gemm8<0><<<dim3(9, 32, 1), 512, 0, stream>>>(xb, wqkvT, nullptr, 0, 2304,
        bqkv, 1.f, qb, kb, vb, 0, 0, 0);

    k_transpose_bf16<<<dim3(24, 64, B), 256, 0, stream>>>(vb, vT, T, C);

    // att = q k^T / sqrt(C): per batch [2048,768] x [2048,768]^T, 8-phase, causal skip
    k_gemm8<1><<<dim3(8, 8, B), 512, 0, stream>>>(qb, kb, att, T, T,
        nullptr, scale, nullptr, nullptr, nullptr,
        (size_t)T * C, (size_t)T * C, (size_t)T * T);

    k_softmax<<<dim3(T, B), 256, 0, stream>>>(att, P, T);

    // y = P v: per batch [2048,2048] x [768,2048]^T, K truncated causally, longest-first
    k_gemm<2><<<dim3(6, 16, B), 256, 0, stream>>>(P, vT, T, T, T,
        (size_t)T * T, (size_t)C * T, (size_t)T * C, y, C, 0, nullptr, 1.f,
        nullptr, nullptr, nullptr);

    // Wh^T after PV so it can overwrite att/P scratch (vectorized transpose)
    k_transpose_wh<<<dim3(Vp / 64, C / 64), 256, 0, stream>>>(Wh, whT, C, V);

    k_layernorm<<<dim3(B * T), 256, 0, stream>>>(y, ln_g, ln_b, yn);

    // logits: [8192,768] x [50432,768]^T -> fp32 d_out; R13 8-phase + XCD swizzle
    k_gemm8<3><<<dim3(Vp / 256, 32), 512, 0, stream>>>(yn, whT, out, V, V,
        bh, 1.f, nullptr, nullptr, nullptr, 0, 0, 0);
}

// Round 15
// 1168.973 us; speedup vs baseline: 1.4062x; 1.0168x over previous
//
#include <hip/hip_runtime.h>
#include <hip/hip_bf16.h>
#include <math.h>

typedef __bf16 bf16x8 __attribute__((ext_vector_type(8)));
typedef float  f32x4  __attribute__((ext_vector_type(4)));

#define GAS(p) ((const __attribute__((address_space(1))) void*)(p))
#define LAS(p) ((__attribute__((address_space(3))) void*)(p))

static constexpr int NE = 768;

// ---------------- embed: x = tok_emb[idx] + pos_emb, -> bf16 ----------------
__global__ __launch_bounds__(256) void k_embed(const int* __restrict__ idx,
    const float* __restrict__ tok, const float* __restrict__ pos,
    __hip_bfloat16* __restrict__ xb)
{
    int bt = blockIdx.x;            // 0..8191
    int t  = bt & 2047;
    int token = idx[bt];
    const float* te = tok + (size_t)token * NE;
    const float* pe = pos + (size_t)t * NE;
    __hip_bfloat16* o = xb + (size_t)bt * NE;
    for (int c = threadIdx.x; c < NE; c += 256)
        o[c] = __float2bfloat16(te[c] + pe[c]);
}

// ------------- transpose fp32 [R][C] -> bf16 [outRows][R] (zero-pad), small weights -------------
__global__ __launch_bounds__(256) void k_transpose_f32_bf16(
    const float* __restrict__ in, __hip_bfloat16* __restrict__ out,
    int R, int C, int outRows)
{
    __shared__ float tile[32][33];
    int c0 = blockIdx.x * 32, r0 = blockIdx.y * 32;
    int tx = threadIdx.x & 31, ty = threadIdx.x >> 5;
    #pragma unroll
    for (int i = 0; i < 32; i += 8) {
        int r = r0 + ty + i, c = c0 + tx;
        tile[ty + i][tx] = (r < R && c < C) ? in[(size_t)r * C + c] : 0.f;
    }
    __syncthreads();
    #pragma unroll
    for (int i = 0; i < 32; i += 8) {
        int oc = c0 + ty + i, orr = r0 + tx;
        if (oc < outRows && orr < R)
            out[(size_t)oc * R + orr] = __float2bfloat16(tile[tx][ty + i]);
    }
}

// ------------- Wh transpose: fp32 [768][50257] -> bf16 [50432][768], vectorized -------------
__global__ __launch_bounds__(256) void k_transpose_wh(
    const float* __restrict__ in, __hip_bfloat16* __restrict__ out,
    int R /*768*/, int C /*50257*/)
{
    __shared__ float tile[64][65];
    const int n0 = blockIdx.x * 64, k0 = blockIdx.y * 64;
    const int t = threadIdx.x;
    if (n0 + 64 <= C) {              // fast path: full float4 tile
        #pragma unroll
        for (int pass = 0; pass < 4; ++pass) {
            int idx = pass * 256 + t;
            int kr = idx >> 4, nc4 = (idx & 15) * 4;
            float4 v = *(const float4*)(in + (size_t)(k0 + kr) * C + n0 + nc4);
            tile[kr][nc4] = v.x; tile[kr][nc4 + 1] = v.y;
            tile[kr][nc4 + 2] = v.z; tile[kr][nc4 + 3] = v.w;
        }
    } else {                         // boundary: guarded scalar
        #pragma unroll
        for (int pass = 0; pass < 16; ++pass) {
            int idx = pass * 256 + t;
            int kr = idx >> 6, nc = idx & 63;
            int c = n0 + nc;
            tile[kr][nc] = (c < C) ? in[(size_t)(k0 + kr) * C + c] : 0.f;
        }
    }
    __syncthreads();
    #pragma unroll
    for (int pass = 0; pass < 2; ++pass) {
        int nr = pass * 32 + (t >> 3);
        int kc = (t & 7) * 8;
        bf16x8 v;
        #pragma unroll
        for (int j = 0; j < 8; ++j) {
            __hip_bfloat16 h = __float2bfloat16(tile[kc + j][nr]);
            v[j] = *reinterpret_cast<__bf16*>(&h);
        }
        *(bf16x8*)(out + (size_t)(n0 + nr) * R + k0 + kc) = v;
    }
}

// ------------- batched bf16 transpose: in [z][R][C] -> out [z][C][R] -------------
__global__ __launch_bounds__(256) void k_transpose_bf16(
    const __hip_bfloat16* __restrict__ in, __hip_bfloat16* __restrict__ out,
    int R, int C)
{
    __shared__ __hip_bfloat16 tile[32][33];
    size_t boff = (size_t)blockIdx.z * R * C;
    int c0 = blockIdx.x * 32, r0 = blockIdx.y * 32;
    int tx = threadIdx.x & 31, ty = threadIdx.x >> 5;
    #pragma unroll
    for (int i = 0; i < 32; i += 8)
        tile[ty + i][tx] = in[boff + (size_t)(r0 + ty + i) * C + (c0 + tx)];
    __syncthreads();
    #pragma unroll
    for (int i = 0; i < 32; i += 8)
        out[boff + (size_t)(c0 + ty + i) * R + (r0 + tx)] = tile[tx][ty + i];
}

__global__ __launch_bounds__(256) void k_pack_bias(const float* __restrict__ bq,
    const float* __restrict__ bk, const float* __restrict__ bv, float* __restrict__ o)
{
    int i = blockIdx.x * 256 + threadIdx.x;
    if (i < 768) o[i] = bq[i];
    else if (i < 1536) o[i] = bk[i - 768];
    else if (i < 2304) o[i] = bv[i - 1536];
}

// ================= PV GEMM: 128x128, BK=64, dbuf, counted vmcnt, 2 blocks/CU =================
// y[bz][2048][768] = P[bz][2048][2048] * Vt[bz][768][2048]^T, K truncated causally to
// (bm+1)*128 (P zero beyond diagonal; NT=(bm+1)*2 always >= 2 and even). Structure =
// R12's numerically-verified head kernel (depth-2 prefetch, vmcnt(8) counted, 64 KiB
// LDS -> 2 blocks/CU); bm reversed so longest blocks dispatch first.
__global__ __launch_bounds__(256, 2) void k_gemm_pv(
    const __hip_bfloat16* __restrict__ Pm,  // [B][2048][2048]
    const __hip_bfloat16* __restrict__ Vt,  // [B][768][2048]
    float* __restrict__ y)                  // [B][2048][768]
{
    constexpr int T = 2048, C = 768;
    __shared__ __align__(16) __hip_bfloat16 As[2][128 * 64];
    __shared__ __align__(16) __hip_bfloat16 Bs[2][128 * 64];

    const int bn = blockIdx.x;                              // 0..5
    const int bm = (int)gridDim.y - 1 - (int)blockIdx.y;    // longest-first
    const int bz = blockIdx.z;
    const int NT = (bm + 1) * 2;                            // K-tiles of 64
    const int tid = threadIdx.x;
    const int w = tid >> 6, lane = tid & 63;
    const int wr = w >> 1, wc = w & 1;                      // wave tile 64x64
    const int lr = lane & 15, lu = lane >> 4;

    const __hip_bfloat16* Ap = Pm + (size_t)bz * T * T + (size_t)(bm * 128) * T;
    const __hip_bfloat16* Bp = Vt + (size_t)bz * C * T + (size_t)(bn * 128) * T;

    f32x4 acc[4][4] = {};

    auto stage = [&](int kt, int pb) {            // 8 loads/thread: 4 A + 4 B chunks
        #pragma unroll
        for (int l = 0; l < 4; ++l) {
            int v = l * 256 + tid;
            int row = v >> 3, u = (v & 7) ^ (row & 7);
            __builtin_amdgcn_global_load_lds(GAS(Ap + (size_t)row * T + kt * 64 + u * 8),
                                             LAS(&As[pb][v * 8]), 16, 0, 0);
        }
        #pragma unroll
        for (int l = 0; l < 4; ++l) {
            int v = l * 256 + tid;
            int row = v >> 3, u = (v & 7) ^ (row & 7);
            __builtin_amdgcn_global_load_lds(GAS(Bp + (size_t)row * T + kt * 64 + u * 8),
                                             LAS(&Bs[pb][v * 8]), 16, 0, 0);
        }
    };
    auto rdA = [&](int pb, int m, int kk) {
        int row = wr * 64 + m * 16 + lr;
        return *(const bf16x8*)&As[pb][row * 64 + (((kk * 4 + lu) ^ (row & 7)) << 3)];
    };
    auto rdB = [&](int pb, int n, int kk) {
        int row = wc * 64 + n * 16 + lr;
        return *(const bf16x8*)&Bs[pb][row * 64 + (((kk * 4 + lu) ^ (row & 7)) << 3)];
    };

    stage(0, 0);
    stage(1, 1);
    asm volatile("s_waitcnt vmcnt(8)" ::: "memory");
    asm volatile("s_barrier" ::: "memory");

    for (int kt = 0; kt < NT; ++kt) {
        const int p = kt & 1;
        bf16x8 af[4][2], bfv[4][2];
        #pragma unroll
        for (int m = 0; m < 4; ++m) { af[m][0] = rdA(p, m, 0); af[m][1] = rdA(p, m, 1); }
        #pragma unroll
        for (int n = 0; n < 4; ++n) { bfv[n][0] = rdB(p, n, 0); bfv[n][1] = rdB(p, n, 1); }
        asm volatile("s_waitcnt lgkmcnt(0)" ::: "memory");  // frags in regs; buf[p] dead
        asm volatile("s_barrier" ::: "memory");             // all waves done with buf[p]
        if (kt + 2 < NT) {
            stage(kt + 2, p);
            asm volatile("s_waitcnt vmcnt(8)" ::: "memory");   // tile kt+1 landed
        } else if (kt + 1 < NT) {
            asm volatile("s_waitcnt vmcnt(0)" ::: "memory");
        }
        asm volatile("s_barrier" ::: "memory");
        __builtin_amdgcn_s_setprio(1);
        #pragma unroll
        for (int m = 0; m < 4; ++m)
            #pragma unroll
            for (int n = 0; n < 4; ++n)
                acc[m][n] = __builtin_amdgcn_mfma_f32_16x16x32_bf16(af[m][0], bfv[n][0], acc[m][n], 0, 0, 0);
        #pragma unroll
        for (int m = 0; m < 4; ++m)
            #pragma unroll
            for (int n = 0; n < 4; ++n)
                acc[m][n] = __builtin_amdgcn_mfma_f32_16x16x32_bf16(af[m][1], bfv[n][1], acc[m][n], 0, 0, 0);
        __builtin_amdgcn_s_setprio(0);
    }

    const int r4 = lu * 4;
    float* yo = y + (size_t)bz * T * C;
    #pragma unroll
    for (int m = 0; m < 4; ++m) {
        #pragma unroll
        for (int n = 0; n < 4; ++n) {
            int col = bn * 128 + wc * 64 + n * 16 + lr;
            #pragma unroll
            for (int r = 0; r < 4; ++r) {
                int row = bm * 128 + wr * 64 + m * 16 + r4 + r;
                yo[(size_t)row * C + col] = acc[m][n][r];
            }
        }
    }
}

// ================= unified 256x256 8-phase GEMM (R13 schedule, verified) =================
// MODE 0: qkv (bf16 out split q/k/v, +bias)  grid (9, 32, 1)
// MODE 1: att (fp32 out * scale, batched, causal 256-tile skip)  grid (8, 8, B)
// MODE 3: head (fp32 out + bias, col-bounded)  grid (197, 32, 1)
template<int MODE>
__global__ __launch_bounds__(512, 2) void k_gemm8(
    const __hip_bfloat16* __restrict__ A, const __hip_bfloat16* __restrict__ Bt,
    float* __restrict__ outf, int ldc, int ncols,
    const float* __restrict__ bias, float scale,
    __hip_bfloat16* __restrict__ oq, __hip_bfloat16* __restrict__ ok,
    __hip_bfloat16* __restrict__ ov,
    size_t strideA, size_t strideB, size_t strideC)
{
    constexpr int K = 768, NT = K / 64, NI = NT / 2;    // 12 tiles, 6 iters
    __shared__ __align__(16) __hip_bfloat16 As[2][2][128 * 64];  // [buf][half]
    __shared__ __align__(16) __hip_bfloat16 Bs[2][2][128 * 64];

    // bijective XCD remap of fast axis
    const int Nx = (int)gridDim.x;
    const int qq = Nx >> 3, rr = Nx & 7;
    const int xcd = (int)blockIdx.x & 7, xidx = (int)blockIdx.x >> 3;
    const int bn = (xcd < rr ? xcd * (qq + 1) : rr * (qq + 1) + (xcd - rr) * qq) + xidx;
    const int bm = blockIdx.y, bz = blockIdx.z;
    if (MODE == 1 && bn > bm) return;   // fully masked causal 256-tile
    const int tid = threadIdx.x;
    const int w = tid >> 6, lane = tid & 63;
    const int wr = w >> 2, wc = w & 3;      // wave = (M-half wr, N-quarter wc)
    const int lr = lane & 15, lu = lane >> 4;

    const int sr = tid >> 3;                // staging row within 64-row chunk
    const int su = (tid & 7) ^ (sr & 7);    // pre-swizzled source 16B unit
    const __hip_bfloat16* Ap = A  + bz * strideA + (size_t)(bm * 256) * K;
    const __hip_bfloat16* Bp = Bt + bz * strideB + (size_t)(bn * 256) * K;

    f32x4 acc[8][4] = {};
    bf16x8 bq[4][2];

    auto stageAh = [&](int t, int h) {      // A half h (128 rows x 64) -> buf t&1
        #pragma unroll
        for (int l = 0; l < 2; ++l)
            __builtin_amdgcn_global_load_lds(
                GAS(Ap + (size_t)(h * 128 + l * 64 + sr) * K + t * 64 + su * 8),
                LAS(&As[t & 1][h][l * 4096 + tid * 8]), 16, 0, 0);
    };
    auto stageBh = [&](int t, int h) {
        #pragma unroll
        for (int l = 0; l < 2; ++l)
            __builtin_amdgcn_global_load_lds(
                GAS(Bp + (size_t)(h * 128 + l * 64 + sr) * K + t * 64 + su * 8),
                LAS(&Bs[t & 1][h][l * 4096 + tid * 8]), 16, 0, 0);
    };
    auto rdA = [&](int b, int q, int f, int kk) {   // wave wr reads only A-half wr
        int row = q * 32 + f * 16 + lr;
        return *(const bf16x8*)&As[b][wr][row * 64 + (((kk * 4 + lu) ^ (row & 7)) << 3)];
    };
    auto rdB = [&](int b, int n, int kk) {          // wave wc reads only B-half wc>>1
        int row = (wc & 1) * 64 + n * 16 + lr;
        return *(const bf16x8*)&Bs[b][wc >> 1][row * 64 + (((kk * 4 + lu) ^ (row & 7)) << 3)];
    };

#define BAR() asm volatile("s_barrier" ::: "memory")
#define VM4() asm volatile("s_waitcnt vmcnt(4)" ::: "memory")
#define VM0() asm volatile("s_waitcnt vmcnt(0)" ::: "memory")
#define CLUSTER(Q)                                                                                          \
    __builtin_amdgcn_s_setprio(1);                                                                          \
    _Pragma("unroll") for (int n = 0; n < 4; ++n)                                                           \
        acc[2*(Q)+0][n] = __builtin_amdgcn_mfma_f32_16x16x32_bf16(af[0][0], bq[n][0], acc[2*(Q)+0][n], 0, 0, 0); \
    _Pragma("unroll") for (int n = 0; n < 4; ++n)                                                           \
        acc[2*(Q)+1][n] = __builtin_amdgcn_mfma_f32_16x16x32_bf16(af[1][0], bq[n][0], acc[2*(Q)+1][n], 0, 0, 0); \
    _Pragma("unroll") for (int n = 0; n < 4; ++n)                                                           \
        acc[2*(Q)+0][n] = __builtin_amdgcn_mfma_f32_16x16x32_bf16(af[0][1], bq[n][1], acc[2*(Q)+0][n], 0, 0, 0); \
    _Pragma("unroll") for (int n = 0; n < 4; ++n)                                                           \
        acc[2*(Q)+1][n] = __builtin_amdgcn_mfma_f32_16x16x32_bf16(af[1][1], bq[n][1], acc[2*(Q)+1][n], 0, 0, 0); \
    __builtin_amdgcn_s_setprio(0);
#define PH(B_, Q_, STAGE)                                                       \
    {   bf16x8 af[2][2];                                                        \
        _Pragma("unroll") for (int f = 0; f < 2; ++f) {                         \
            af[f][0] = rdA(B_, Q_, f, 0); af[f][1] = rdA(B_, Q_, f, 1); }       \
        STAGE                                                                   \
        CLUSTER(Q_)                                                             \
        BAR(); }
#define PHV(B_, Q_, STAGE, VMSTMT)                                              \
    {   bf16x8 af[2][2];                                                        \
        _Pragma("unroll") for (int f = 0; f < 2; ++f) {                         \
            af[f][0] = rdA(B_, Q_, f, 0); af[f][1] = rdA(B_, Q_, f, 1); }       \
        STAGE                                                                   \
        VMSTMT                                                                  \
        BAR();                                                                  \
        CLUSTER(Q_)                                                             \
        BAR(); }

    // prologue: B(0),A(0),B(1) = 12 loads; VM4 retires tile-0's 8, leaves B(1)'s 4
    stageBh(0, 0); stageBh(0, 1);
    stageAh(0, 0); stageAh(0, 1);
    stageBh(1, 0); stageBh(1, 1);
    VM4();
    BAR();

    for (int i = 0; i < NI; ++i) {
        const int t0 = 2 * i, t1 = 2 * i + 1;
        const bool full = (i + 1 < NI);
        // ---- tile t0 (buf 0) ----
        #pragma unroll
        for (int n = 0; n < 4; ++n) { bq[n][0] = rdB(0, n, 0); bq[n][1] = rdB(0, n, 1); }
        PH(0, 0, { stageAh(t1, 0); stageAh(t1, 1); })
        PH(0, 1, { if (full) stageBh(t0 + 2, 0); })
        PH(0, 2, { if (full) stageBh(t0 + 2, 1); })
        PHV(0, 3, { }, { if (full) { VM4(); } else { VM0(); } })
        // ---- tile t1 (buf 1) ----
        #pragma unroll
        for (int n = 0; n < 4; ++n) { bq[n][0] = rdB(1, n, 0); bq[n][1] = rdB(1, n, 1); }
        PH(1, 0, { if (full) stageAh(t0 + 2, 0); })
        PH(1, 1, { if (full) stageAh(t0 + 2, 1); })
        PH(1, 2, { if (full) stageBh(t1 + 2, 0); })
        PHV(1, 3, { if (full) stageBh(t1 + 2, 1); }, { if (full) { VM4(); } else { VM0(); } })
    }
#undef PHV
#undef PH
#undef CLUSTER
#undef VM0
#undef VM4
#undef BAR

    // epilogue: row = bm*256 + wr*128 + m*16 + lu*4 + r, col = bn*256 + wc*64 + n*16 + lr
    const int r4 = lu * 4;
    #pragma unroll
    for (int m = 0; m < 8; ++m) {
        #pragma unroll
        for (int n = 0; n < 4; ++n) {
            int col = bn * 256 + wc * 64 + n * 16 + lr;
            if constexpr (MODE == 0) {
                float bv_ = bias[col];
                #pragma unroll
                for (int r = 0; r < 4; ++r) {
                    int row = bm * 256 + wr * 128 + m * 16 + r4 + r;
                    __hip_bfloat16 h = __float2bfloat16(acc[m][n][r] + bv_);
                    if (col < 768)       oq[(size_t)row * 768 + col]          = h;
                    else if (col < 1536) ok[(size_t)row * 768 + (col - 768)]  = h;
                    else                 ov[(size_t)row * 768 + (col - 1536)] = h;
                }
            } else if constexpr (MODE == 1) {
                #pragma unroll
                for (int r = 0; r < 4; ++r) {
                    int row = bm * 256 + wr * 128 + m * 16 + r4 + r;
                    outf[bz * strideC + (size_t)row * ldc + col] = acc[m][n][r] * scale;
                }
            } else {
                if (col < ncols) {
                    float bv_ = bias[col];
                    #pragma unroll
                    for (int r = 0; r < 4; ++r) {
                        int row = bm * 256 + wr * 128 + m * 16 + r4 + r;
                        outf[(size_t)row * ldc + col] = acc[m][n][r] + bv_;
                    }
                }
            }
        }
    }
}

// ---------------- causal softmax: float4 loads, __expf, zero-fill to 128-boundary ----------------
__global__ __launch_bounds__(256) void k_softmax(const float* __restrict__ att,
    __hip_bfloat16* __restrict__ P, int T)
{
    int t = blockIdx.x, b = blockIdx.y;
    const float* row = att + ((size_t)b * T + t) * T;
    __hip_bfloat16* prow = P + ((size_t)b * T + t) * T;
    const int n = t + 1;
    const int nz = ((t >> 7) + 1) << 7;     // PV (truncated, 128-tiles) reads only cols < nz
    __shared__ float red[256];
    float4 v[2];
    float mx = -1e30f;
    #pragma unroll
    for (int j = 0; j < 2; ++j) {
        int e = (threadIdx.x + j * 256) * 4;
        v[j] = *(const float4*)(row + e);
        #pragma unroll
        for (int k = 0; k < 4; ++k)
            if (e + k < n) mx = fmaxf(mx, ((const float*)&v[j])[k]);
    }
    red[threadIdx.x] = mx; __syncthreads();
    for (int o = 128; o > 0; o >>= 1) {
        if (threadIdx.x < o) red[threadIdx.x] = fmaxf(red[threadIdx.x], red[threadIdx.x + o]);
        __syncthreads();
    }
    mx = red[0]; __syncthreads();
    float ev[8];
    float sum = 0.f;
    #pragma unroll
    for (int j = 0; j < 2; ++j) {
        int e = (threadIdx.x + j * 256) * 4;
        #pragma unroll
        for (int k = 0; k < 4; ++k) {
            float x = ((const float*)&v[j])[k];
            float ex = (e + k < n) ? __expf(x - mx) : 0.f;
            ev[j * 4 + k] = ex;
            sum += ex;
        }
    }
    red[threadIdx.x] = sum; __syncthreads();
    for (int o = 128; o > 0; o >>= 1) {
        if (threadIdx.x < o) red[threadIdx.x] += red[threadIdx.x + o];
        __syncthreads();
    }
    float inv = 1.f / red[0];
    #pragma unroll
    for (int j = 0; j < 2; ++j) {
        int e = (threadIdx.x + j * 256) * 4;
        #pragma unroll
        for (int k = 0; k < 4; ++k)
            if (e + k < nz) prow[e + k] = __float2bfloat16(ev[j * 4 + k] * inv);
    }
}

// ---------------- LayerNorm (eps 1e-5) fp32 -> bf16 ----------------
__global__ __launch_bounds__(256) void k_layernorm(const float* __restrict__ y,
    const float* __restrict__ g, const float* __restrict__ b,
    __hip_bfloat16* __restrict__ yn)
{
    int row = blockIdx.x;
    const float* yr = y + (size_t)row * NE;
    float s = 0.f, s2 = 0.f;
    for (int c = threadIdx.x; c < NE; c += 256) { float v = yr[c]; s += v; s2 += v * v; }
    __shared__ float r1[256], r2[256];
    r1[threadIdx.x] = s; r2[threadIdx.x] = s2; __syncthreads();
    for (int o = 128; o > 0; o >>= 1) {
        if (threadIdx.x < o) { r1[threadIdx.x] += r1[threadIdx.x + o]; r2[threadIdx.x] += r2[threadIdx.x + o]; }
        __syncthreads();
    }
    float mu = r1[0] / NE;
    float var = r2[0] / NE - mu * mu;
    float rs = rsqrtf(var + 1e-5f);
    __hip_bfloat16* o = yn + (size_t)row * NE;
    for (int c = threadIdx.x; c < NE; c += 256)
        o[c] = __float2bfloat16((yr[c] - mu) * rs * g[c] + b[c]);
}

extern "C" void kernel_launch(void* const* d_in, const int* in_sizes, int n_in,
                              void* d_out, int out_size, void* d_ws, size_t ws_size,
                              hipStream_t stream)
{
    const int*   idx  = (const int*)  d_in[0];
    const float* tok  = (const float*)d_in[1];
    const float* pos  = (const float*)d_in[2];
    const float* Wq   = (const float*)d_in[3];
    const float* bq   = (const float*)d_in[4];
    const float* Wk   = (const float*)d_in[5];
    const float* bk   = (const float*)d_in[6];
    const float* Wv   = (const float*)d_in[7];
    const float* bv   = (const float*)d_in[8];
    const float* ln_g = (const float*)d_in[9];
    const float* ln_b = (const float*)d_in[10];
    const float* Wh   = (const float*)d_in[11];
    const float* bh   = (const float*)d_in[12];
    float* out = (float*)d_out;

    const int B = 4, T = 2048, C = 768, V = 50257, Vp = 50432;  // Vp = 197*256 = 788*64

    char* p = (char*)d_ws;
    auto take = [&](size_t bytes) { char* r = p; p += (bytes + 255) & ~(size_t)255; return r; };
    __hip_bfloat16* xb    = (__hip_bfloat16*)take((size_t)B * T * C * 2);
    __hip_bfloat16* wqkvT = (__hip_bfloat16*)take((size_t)3 * C * C * 2);
    float*          bqkv  = (float*)take((size_t)3 * C * 4);
    __hip_bfloat16* qb    = (__hip_bfloat16*)take((size_t)B * T * C * 2);
    __hip_bfloat16* kb    = (__hip_bfloat16*)take((size_t)B * T * C * 2);
    __hip_bfloat16* vb    = (__hip_bfloat16*)take((size_t)B * T * C * 2);
    __hip_bfloat16* vT    = (__hip_bfloat16*)take((size_t)B * T * C * 2);
    float*          att   = (float*)take((size_t)B * T * T * 4);
    __hip_bfloat16* P     = (__hip_bfloat16*)take((size_t)B * T * T * 2);
    float*          y     = (float*)take((size_t)B * T * C * 4);
    __hip_bfloat16* yn    = (__hip_bfloat16*)take((size_t)B * T * C * 2);
    // Wh^T (77.4 MB, Vp rows) reuses the att+P region (100.6 MB) — dead once y exists.
    __hip_bfloat16* whT   = (__hip_bfloat16*)att;

    float scale = 1.0f / sqrtf((float)C);

    k_embed<<<dim3(B * T), 256, 0, stream>>>(idx, tok, pos, xb);
    k_transpose_f32_bf16<<<dim3(24, 24), 256, 0, stream>>>(Wq, wqkvT,             C, C, C);
    k_transpose_f32_bf16<<<dim3(24, 24), 256, 0, stream>>>(Wk, wqkvT + C * C,     C, C, C);
    k_transpose_f32_bf16<<<dim3(24, 24), 256, 0, stream>>>(Wv, wqkvT + 2 * C * C, C, C, C);
    k_pack_bias<<<dim3(9), 256, 0, stream>>>(bq, bk, bv, bqkv);

    // qkv: [8192,768] x [2304,768]^T, 8-phase kernel
    k_gemm8<0><<<dim3(9, 32, 1), 512, 0, stream>>>(xb, wqkvT, nullptr, 0, 2304,
        bqkv, 1.f, qb, kb, vb, 0, 0, 0);

    k_transpose_bf16<<<dim3(24, 64, B), 256, 0, stream>>>(vb, vT, T, C);

    // att = q k^T / sqrt(C): per batch [2048,768] x [2048,768]^T, 8-phase, causal skip
    k_gemm8<1><<<dim3(8, 8, B), 512, 0, stream>>>(qb, kb, att, T, T,
        nullptr, scale, nullptr, nullptr, nullptr,
        (size_t)T * C, (size_t)T * C, (size_t)T * T);

    k_softmax<<<dim3(T, B), 256, 0, stream>>>(att, P, T);

    // y = P v: per batch [2048,2048] x [768,2048]^T, causal-truncated dbuf kernel
    k_gemm_pv<<<dim3(6, 16, B), 256, 0, stream>>>(P, vT, y);

    // Wh^T after PV so it can overwrite att/P scratch (vectorized transpose)
    k_transpose_wh<<<dim3(Vp / 64, C / 64), 256, 0, stream>>>(Wh, whT, C, V);

    k_layernorm<<<dim3(B * T), 256, 0, stream>>>(y, ln_g, ln_b, yn);

    // logits: [8192,768] x [50432,768]^T -> fp32 d_out; R13 8-phase + XCD swizzle
    k_gemm8<3><<<dim3(Vp / 256, 32), 512, 0, stream>>>(yn, whT, out, V, V,
        bh, 1.f, nullptr, nullptr, nullptr, 0, 0, 0);
}

// Round 16
// 1158.368 us; speedup vs baseline: 1.4190x; 1.0092x over previous
//
#include <hip/hip_runtime.h>
#include <hip/hip_bf16.h>
#include <math.h>

typedef __bf16 bf16x8 __attribute__((ext_vector_type(8)));
typedef float  f32x4  __attribute__((ext_vector_type(4)));

#define GAS(p) ((const __attribute__((address_space(1))) void*)(p))
#define LAS(p) ((__attribute__((address_space(3))) void*)(p))

static constexpr int NE = 768;

// ---------------- embed: x = tok_emb[idx] + pos_emb, -> bf16 (float4 / bf16x8) ----------------
__global__ __launch_bounds__(256) void k_embed(const int* __restrict__ idx,
    const float* __restrict__ tok, const float* __restrict__ pos,
    __hip_bfloat16* __restrict__ xb)
{
    int bt = blockIdx.x;            // 0..8191
    int t  = bt & 2047;
    int token = idx[bt];
    const float* te = tok + (size_t)token * NE;
    const float* pe = pos + (size_t)t * NE;
    __hip_bfloat16* o = xb + (size_t)bt * NE;
    int tid = threadIdx.x;
    if (tid < 96) {                 // 96 lanes x 8 elems = 768
        int c = tid * 8;
        float4 a0 = *(const float4*)(te + c),     p0 = *(const float4*)(pe + c);
        float4 a1 = *(const float4*)(te + c + 4), p1 = *(const float4*)(pe + c + 4);
        float s[8] = { a0.x + p0.x, a0.y + p0.y, a0.z + p0.z, a0.w + p0.w,
                       a1.x + p1.x, a1.y + p1.y, a1.z + p1.z, a1.w + p1.w };
        bf16x8 v;
        #pragma unroll
        for (int j = 0; j < 8; ++j) {
            __hip_bfloat16 h = __float2bfloat16(s[j]);
            v[j] = *reinterpret_cast<__bf16*>(&h);
        }
        *(bf16x8*)(o + c) = v;
    }
}

// ------------- transpose fp32 [R][C] -> bf16 [outRows][R] (zero-pad), small weights -------------
__global__ __launch_bounds__(256) void k_transpose_f32_bf16(
    const float* __restrict__ in, __hip_bfloat16* __restrict__ out,
    int R, int C, int outRows)
{
    __shared__ float tile[32][33];
    int c0 = blockIdx.x * 32, r0 = blockIdx.y * 32;
    int tx = threadIdx.x & 31, ty = threadIdx.x >> 5;
    #pragma unroll
    for (int i = 0; i < 32; i += 8) {
        int r = r0 + ty + i, c = c0 + tx;
        tile[ty + i][tx] = (r < R && c < C) ? in[(size_t)r * C + c] : 0.f;
    }
    __syncthreads();
    #pragma unroll
    for (int i = 0; i < 32; i += 8) {
        int oc = c0 + ty + i, orr = r0 + tx;
        if (oc < outRows && orr < R)
            out[(size_t)oc * R + orr] = __float2bfloat16(tile[tx][ty + i]);
    }
}

// ------------- Wh transpose: fp32 [768][50257] -> bf16 [50432][768], vectorized -------------
__global__ __launch_bounds__(256) void k_transpose_wh(
    const float* __restrict__ in, __hip_bfloat16* __restrict__ out,
    int R /*768*/, int C /*50257*/)
{
    __shared__ float tile[64][65];
    const int n0 = blockIdx.x * 64, k0 = blockIdx.y * 64;
    const int t = threadIdx.x;
    if (n0 + 64 <= C) {              // fast path: full float4 tile
        #pragma unroll
        for (int pass = 0; pass < 4; ++pass) {
            int idx = pass * 256 + t;
            int kr = idx >> 4, nc4 = (idx & 15) * 4;
            float4 v = *(const float4*)(in + (size_t)(k0 + kr) * C + n0 + nc4);
            tile[kr][nc4] = v.x; tile[kr][nc4 + 1] = v.y;
            tile[kr][nc4 + 2] = v.z; tile[kr][nc4 + 3] = v.w;
        }
    } else {                         // boundary: guarded scalar
        #pragma unroll
        for (int pass = 0; pass < 16; ++pass) {
            int idx = pass * 256 + t;
            int kr = idx >> 6, nc = idx & 63;
            int c = n0 + nc;
            tile[kr][nc] = (c < C) ? in[(size_t)(k0 + kr) * C + c] : 0.f;
        }
    }
    __syncthreads();
    #pragma unroll
    for (int pass = 0; pass < 2; ++pass) {
        int nr = pass * 32 + (t >> 3);
        int kc = (t & 7) * 8;
        bf16x8 v;
        #pragma unroll
        for (int j = 0; j < 8; ++j) {
            __hip_bfloat16 h = __float2bfloat16(tile[kc + j][nr]);
            v[j] = *reinterpret_cast<__bf16*>(&h);
        }
        *(bf16x8*)(out + (size_t)(n0 + nr) * R + k0 + kc) = v;
    }
}

// ------------- batched bf16 transpose: in [z][R][C] -> out [z][C][R] -------------
__global__ __launch_bounds__(256) void k_transpose_bf16(
    const __hip_bfloat16* __restrict__ in, __hip_bfloat16* __restrict__ out,
    int R, int C)
{
    __shared__ __hip_bfloat16 tile[32][33];
    size_t boff = (size_t)blockIdx.z * R * C;
    int c0 = blockIdx.x * 32, r0 = blockIdx.y * 32;
    int tx = threadIdx.x & 31, ty = threadIdx.x >> 5;
    #pragma unroll
    for (int i = 0; i < 32; i += 8)
        tile[ty + i][tx] = in[boff + (size_t)(r0 + ty + i) * C + (c0 + tx)];
    __syncthreads();
    #pragma unroll
    for (int i = 0; i < 32; i += 8)
        out[boff + (size_t)(c0 + ty + i) * R + (r0 + tx)] = tile[tx][ty + i];
}

__global__ __launch_bounds__(256) void k_pack_bias(const float* __restrict__ bq,
    const float* __restrict__ bk, const float* __restrict__ bv, float* __restrict__ o)
{
    int i = blockIdx.x * 256 + threadIdx.x;
    if (i < 768) o[i] = bq[i];
    else if (i < 1536) o[i] = bk[i - 768];
    else if (i < 2304) o[i] = bv[i - 1536];
}

// ================= PV GEMM: 128x128, BK=64, dbuf, counted vmcnt, 2 blocks/CU =================
__global__ __launch_bounds__(256, 2) void k_gemm_pv(
    const __hip_bfloat16* __restrict__ Pm,  // [B][2048][2048]
    const __hip_bfloat16* __restrict__ Vt,  // [B][768][2048]
    float* __restrict__ y)                  // [B][2048][768]
{
    constexpr int T = 2048, C = 768;
    __shared__ __align__(16) __hip_bfloat16 As[2][128 * 64];
    __shared__ __align__(16) __hip_bfloat16 Bs[2][128 * 64];

    const int bn = blockIdx.x;                              // 0..5
    const int bm = (int)gridDim.y - 1 - (int)blockIdx.y;    // longest-first
    const int bz = blockIdx.z;
    const int NT = (bm + 1) * 2;                            // K-tiles of 64
    const int tid = threadIdx.x;
    const int w = tid >> 6, lane = tid & 63;
    const int wr = w >> 1, wc = w & 1;                      // wave tile 64x64
    const int lr = lane & 15, lu = lane >> 4;

    const __hip_bfloat16* Ap = Pm + (size_t)bz * T * T + (size_t)(bm * 128) * T;
    const __hip_bfloat16* Bp = Vt + (size_t)bz * C * T + (size_t)(bn * 128) * T;

    f32x4 acc[4][4] = {};

    auto stage = [&](int kt, int pb) {            // 8 loads/thread: 4 A + 4 B chunks
        #pragma unroll
        for (int l = 0; l < 4; ++l) {
            int v = l * 256 + tid;
            int row = v >> 3, u = (v & 7) ^ (row & 7);
            __builtin_amdgcn_global_load_lds(GAS(Ap + (size_t)row * T + kt * 64 + u * 8),
                                             LAS(&As[pb][v * 8]), 16, 0, 0);
        }
        #pragma unroll
        for (int l = 0; l < 4; ++l) {
            int v = l * 256 + tid;
            int row = v >> 3, u = (v & 7) ^ (row & 7);
            __builtin_amdgcn_global_load_lds(GAS(Bp + (size_t)row * T + kt * 64 + u * 8),
                                             LAS(&Bs[pb][v * 8]), 16, 0, 0);
        }
    };
    auto rdA = [&](int pb, int m, int kk) {
        int row = wr * 64 + m * 16 + lr;
        return *(const bf16x8*)&As[pb][row * 64 + (((kk * 4 + lu) ^ (row & 7)) << 3)];
    };
    auto rdB = [&](int pb, int n, int kk) {
        int row = wc * 64 + n * 16 + lr;
        return *(const bf16x8*)&Bs[pb][row * 64 + (((kk * 4 + lu) ^ (row & 7)) << 3)];
    };

    stage(0, 0);
    stage(1, 1);
    asm volatile("s_waitcnt vmcnt(8)" ::: "memory");
    asm volatile("s_barrier" ::: "memory");

    for (int kt = 0; kt < NT; ++kt) {
        const int p = kt & 1;
        bf16x8 af[4][2], bfv[4][2];
        #pragma unroll
        for (int m = 0; m < 4; ++m) { af[m][0] = rdA(p, m, 0); af[m][1] = rdA(p, m, 1); }
        #pragma unroll
        for (int n = 0; n < 4; ++n) { bfv[n][0] = rdB(p, n, 0); bfv[n][1] = rdB(p, n, 1); }
        asm volatile("s_waitcnt lgkmcnt(0)" ::: "memory");  // frags in regs; buf[p] dead
        asm volatile("s_barrier" ::: "memory");             // all waves done with buf[p]
        if (kt + 2 < NT) {
            stage(kt + 2, p);
            asm volatile("s_waitcnt vmcnt(8)" ::: "memory");   // tile kt+1 landed
        } else if (kt + 1 < NT) {
            asm volatile("s_waitcnt vmcnt(0)" ::: "memory");
        }
        asm volatile("s_barrier" ::: "memory");
        __builtin_amdgcn_s_setprio(1);
        #pragma unroll
        for (int m = 0; m < 4; ++m)
            #pragma unroll
            for (int n = 0; n < 4; ++n)
                acc[m][n] = __builtin_amdgcn_mfma_f32_16x16x32_bf16(af[m][0], bfv[n][0], acc[m][n], 0, 0, 0);
        #pragma unroll
        for (int m = 0; m < 4; ++m)
            #pragma unroll
            for (int n = 0; n < 4; ++n)
                acc[m][n] = __builtin_amdgcn_mfma_f32_16x16x32_bf16(af[m][1], bfv[n][1], acc[m][n], 0, 0, 0);
        __builtin_amdgcn_s_setprio(0);
    }

    const int r4 = lu * 4;
    float* yo = y + (size_t)bz * T * C;
    #pragma unroll
    for (int m = 0; m < 4; ++m) {
        #pragma unroll
        for (int n = 0; n < 4; ++n) {
            int col = bn * 128 + wc * 64 + n * 16 + lr;
            #pragma unroll
            for (int r = 0; r < 4; ++r) {
                int row = bm * 128 + wr * 64 + m * 16 + r4 + r;
                yo[(size_t)row * C + col] = acc[m][n][r];
            }
        }
    }
}

// ================= unified 256x256 8-phase GEMM (R13 schedule, verified) =================
// MODE 0: qkv (bf16 out split q/k/v, +bias)  grid (9, 32, 1)
// MODE 1: att (fp32 out * scale, batched, causal 256-tile skip)  grid (8, 8, B)
// MODE 3: head (fp32 out + bias, col-bounded)  grid (197, 32, 1)
template<int MODE>
__global__ __launch_bounds__(512, 2) void k_gemm8(
    const __hip_bfloat16* __restrict__ A, const __hip_bfloat16* __restrict__ Bt,
    float* __restrict__ outf, int ldc, int ncols,
    const float* __restrict__ bias, float scale,
    __hip_bfloat16* __restrict__ oq, __hip_bfloat16* __restrict__ ok,
    __hip_bfloat16* __restrict__ ov,
    size_t strideA, size_t strideB, size_t strideC)
{
    constexpr int K = 768, NT = K / 64, NI = NT / 2;    // 12 tiles, 6 iters
    __shared__ __align__(16) __hip_bfloat16 As[2][2][128 * 64];  // [buf][half]
    __shared__ __align__(16) __hip_bfloat16 Bs[2][2][128 * 64];

    // bijective XCD remap of fast axis
    const int Nx = (int)gridDim.x;
    const int qq = Nx >> 3, rr = Nx & 7;
    const int xcd = (int)blockIdx.x & 7, xidx = (int)blockIdx.x >> 3;
    const int bn = (xcd < rr ? xcd * (qq + 1) : rr * (qq + 1) + (xcd - rr) * qq) + xidx;
    const int bm = blockIdx.y, bz = blockIdx.z;
    if (MODE == 1 && bn > bm) return;   // fully masked causal 256-tile
    const int tid = threadIdx.x;
    const int w = tid >> 6, lane = tid & 63;
    const int wr = w >> 2, wc = w & 3;      // wave = (M-half wr, N-quarter wc)
    const int lr = lane & 15, lu = lane >> 4;

    const int sr = tid >> 3;                // staging row within 64-row chunk
    const int su = (tid & 7) ^ (sr & 7);    // pre-swizzled source 16B unit
    const __hip_bfloat16* Ap = A  + bz * strideA + (size_t)(bm * 256) * K;
    const __hip_bfloat16* Bp = Bt + bz * strideB + (size_t)(bn * 256) * K;

    f32x4 acc[8][4] = {};
    bf16x8 bq[4][2];

    auto stageAh = [&](int t, int h) {      // A half h (128 rows x 64) -> buf t&1
        #pragma unroll
        for (int l = 0; l < 2; ++l)
            __builtin_amdgcn_global_load_lds(
                GAS(Ap + (size_t)(h * 128 + l * 64 + sr) * K + t * 64 + su * 8),
                LAS(&As[t & 1][h][l * 4096 + tid * 8]), 16, 0, 0);
    };
    auto stageBh = [&](int t, int h) {
        #pragma unroll
        for (int l = 0; l < 2; ++l)
            __builtin_amdgcn_global_load_lds(
                GAS(Bp + (size_t)(h * 128 + l * 64 + sr) * K + t * 64 + su * 8),
                LAS(&Bs[t & 1][h][l * 4096 + tid * 8]), 16, 0, 0);
    };
    auto rdA = [&](int b, int q, int f, int kk) {   // wave wr reads only A-half wr
        int row = q * 32 + f * 16 + lr;
        return *(const bf16x8*)&As[b][wr][row * 64 + (((kk * 4 + lu) ^ (row & 7)) << 3)];
    };
    auto rdB = [&](int b, int n, int kk) {          // wave wc reads only B-half wc>>1
        int row = (wc & 1) * 64 + n * 16 + lr;
        return *(const bf16x8*)&Bs[b][wc >> 1][row * 64 + (((kk * 4 + lu) ^ (row & 7)) << 3)];
    };

#define BAR() asm volatile("s_barrier" ::: "memory")
#define VM4() asm volatile("s_waitcnt vmcnt(4)" ::: "memory")
#define VM0() asm volatile("s_waitcnt vmcnt(0)" ::: "memory")
#define CLUSTER(Q)                                                                                          \
    __builtin_amdgcn_s_setprio(1);                                                                          \
    _Pragma("unroll") for (int n = 0; n < 4; ++n)                                                           \
        acc[2*(Q)+0][n] = __builtin_amdgcn_mfma_f32_16x16x32_bf16(af[0][0], bq[n][0], acc[2*(Q)+0][n], 0, 0, 0); \
    _Pragma("unroll") for (int n = 0; n < 4; ++n)                                                           \
        acc[2*(Q)+1][n] = __builtin_amdgcn_mfma_f32_16x16x32_bf16(af[1][0], bq[n][0], acc[2*(Q)+1][n], 0, 0, 0); \
    _Pragma("unroll") for (int n = 0; n < 4; ++n)                                                           \
        acc[2*(Q)+0][n] = __builtin_amdgcn_mfma_f32_16x16x32_bf16(af[0][1], bq[n][1], acc[2*(Q)+0][n], 0, 0, 0); \
    _Pragma("unroll") for (int n = 0; n < 4; ++n)                                                           \
        acc[2*(Q)+1][n] = __builtin_amdgcn_mfma_f32_16x16x32_bf16(af[1][1], bq[n][1], acc[2*(Q)+1][n], 0, 0, 0); \
    __builtin_amdgcn_s_setprio(0);
#define PH(B_, Q_, STAGE)                                                       \
    {   bf16x8 af[2][2];                                                        \
        _Pragma("unroll") for (int f = 0; f < 2; ++f) {                         \
            af[f][0] = rdA(B_, Q_, f, 0); af[f][1] = rdA(B_, Q_, f, 1); }       \
        STAGE                                                                   \
        CLUSTER(Q_)                                                             \
        BAR(); }
#define PHV(B_, Q_, STAGE, VMSTMT)                                              \
    {   bf16x8 af[2][2];                                                        \
        _Pragma("unroll") for (int f = 0; f < 2; ++f) {                         \
            af[f][0] = rdA(B_, Q_, f, 0); af[f][1] = rdA(B_, Q_, f, 1); }       \
        STAGE                                                                   \
        VMSTMT                                                                  \
        BAR();                                                                  \
        CLUSTER(Q_)                                                             \
        BAR(); }

    // prologue: B(0),A(0),B(1) = 12 loads; VM4 retires tile-0's 8, leaves B(1)'s 4
    stageBh(0, 0); stageBh(0, 1);
    stageAh(0, 0); stageAh(0, 1);
    stageBh(1, 0); stageBh(1, 1);
    VM4();
    BAR();

    for (int i = 0; i < NI; ++i) {
        const int t0 = 2 * i, t1 = 2 * i + 1;
        const bool full = (i + 1 < NI);
        // ---- tile t0 (buf 0) ----
        #pragma unroll
        for (int n = 0; n < 4; ++n) { bq[n][0] = rdB(0, n, 0); bq[n][1] = rdB(0, n, 1); }
        PH(0, 0, { stageAh(t1, 0); stageAh(t1, 1); })
        PH(0, 1, { if (full) stageBh(t0 + 2, 0); })
        PH(0, 2, { if (full) stageBh(t0 + 2, 1); })
        PHV(0, 3, { }, { if (full) { VM4(); } else { VM0(); } })
        // ---- tile t1 (buf 1) ----
        #pragma unroll
        for (int n = 0; n < 4; ++n) { bq[n][0] = rdB(1, n, 0); bq[n][1] = rdB(1, n, 1); }
        PH(1, 0, { if (full) stageAh(t0 + 2, 0); })
        PH(1, 1, { if (full) stageAh(t0 + 2, 1); })
        PH(1, 2, { if (full) stageBh(t1 + 2, 0); })
        PHV(1, 3, { if (full) stageBh(t1 + 2, 1); }, { if (full) { VM4(); } else { VM0(); } })
    }
#undef PHV
#undef PH
#undef CLUSTER
#undef VM0
#undef VM4
#undef BAR

    // epilogue: row = bm*256 + wr*128 + m*16 + lu*4 + r, col = bn*256 + wc*64 + n*16 + lr
    const int r4 = lu * 4;
    #pragma unroll
    for (int m = 0; m < 8; ++m) {
        #pragma unroll
        for (int n = 0; n < 4; ++n) {
            int col = bn * 256 + wc * 64 + n * 16 + lr;
            if constexpr (MODE == 0) {
                float bv_ = bias[col];
                #pragma unroll
                for (int r = 0; r < 4; ++r) {
                    int row = bm * 256 + wr * 128 + m * 16 + r4 + r;
                    __hip_bfloat16 h = __float2bfloat16(acc[m][n][r] + bv_);
                    if (col < 768)       oq[(size_t)row * 768 + col]          = h;
                    else if (col < 1536) ok[(size_t)row * 768 + (col - 768)]  = h;
                    else                 ov[(size_t)row * 768 + (col - 1536)] = h;
                }
            } else if constexpr (MODE == 1) {
                #pragma unroll
                for (int r = 0; r < 4; ++r) {
                    int row = bm * 256 + wr * 128 + m * 16 + r4 + r;
                    outf[bz * strideC + (size_t)row * ldc + col] = acc[m][n][r] * scale;
                }
            } else {
                if (col < ncols) {
                    float bv_ = bias[col];
                    #pragma unroll
                    for (int r = 0; r < 4; ++r) {
                        int row = bm * 256 + wr * 128 + m * 16 + r4 + r;
                        outf[(size_t)row * ldc + col] = acc[m][n][r] + bv_;
                    }
                }
            }
        }
    }
}

// ---------------- causal softmax: float4 loads, __expf, zero-fill to 128-boundary ----------------
__global__ __launch_bounds__(256) void k_softmax(const float* __restrict__ att,
    __hip_bfloat16* __restrict__ P, int T)
{
    int t = blockIdx.x, b = blockIdx.y;
    const float* row = att + ((size_t)b * T + t) * T;
    __hip_bfloat16* prow = P + ((size_t)b * T + t) * T;
    const int n = t + 1;
    const int nz = ((t >> 7) + 1) << 7;     // PV (truncated, 128-tiles) reads only cols < nz
    __shared__ float red[256];
    float4 v[2];
    float mx = -1e30f;
    #pragma unroll
    for (int j = 0; j < 2; ++j) {
        int e = (threadIdx.x + j * 256) * 4;
        v[j] = *(const float4*)(row + e);
        #pragma unroll
        for (int k = 0; k < 4; ++k)
            if (e + k < n) mx = fmaxf(mx, ((const float*)&v[j])[k]);
    }
    red[threadIdx.x] = mx; __syncthreads();
    for (int o = 128; o > 0; o >>= 1) {
        if (threadIdx.x < o) red[threadIdx.x] = fmaxf(red[threadIdx.x], red[threadIdx.x + o]);
        __syncthreads();
    }
    mx = red[0]; __syncthreads();
    float ev[8];
    float sum = 0.f;
    #pragma unroll
    for (int j = 0; j < 2; ++j) {
        int e = (threadIdx.x + j * 256) * 4;
        #pragma unroll
        for (int k = 0; k < 4; ++k) {
            float x = ((const float*)&v[j])[k];
            float ex = (e + k < n) ? __expf(x - mx) : 0.f;
            ev[j * 4 + k] = ex;
            sum += ex;
        }
    }
    red[threadIdx.x] = sum; __syncthreads();
    for (int o = 128; o > 0; o >>= 1) {
        if (threadIdx.x < o) red[threadIdx.x] += red[threadIdx.x + o];
        __syncthreads();
    }
    float inv = 1.f / red[0];
    #pragma unroll
    for (int j = 0; j < 2; ++j) {
        int e = (threadIdx.x + j * 256) * 4;
        #pragma unroll
        for (int k = 0; k < 4; ++k)
            if (e + k < nz) prow[e + k] = __float2bfloat16(ev[j * 4 + k] * inv);
    }
}

// ---------------- LayerNorm (eps 1e-5) fp32 -> bf16, float4 loads + register stash ----------------
__global__ __launch_bounds__(256) void k_layernorm(const float* __restrict__ y,
    const float* __restrict__ g, const float* __restrict__ b,
    __hip_bfloat16* __restrict__ yn)
{
    int row = blockIdx.x;
    const float* yr = y + (size_t)row * NE;
    int tid = threadIdx.x;
    float4 v = make_float4(0.f, 0.f, 0.f, 0.f);
    float s = 0.f, s2 = 0.f;
    if (tid < 192) {                       // 192 x 4 = 768
        v = *(const float4*)(yr + tid * 4);
        s  = v.x + v.y + v.z + v.w;
        s2 = v.x * v.x + v.y * v.y + v.z * v.z + v.w * v.w;
    }
    __shared__ float r1[256], r2[256];
    r1[tid] = s; r2[tid] = s2; __syncthreads();
    for (int o = 128; o > 0; o >>= 1) {
        if (tid < o) { r1[tid] += r1[tid + o]; r2[tid] += r2[tid + o]; }
        __syncthreads();
    }
    float mu = r1[0] / NE;
    float var = r2[0] / NE - mu * mu;
    float rs = rsqrtf(var + 1e-5f);
    if (tid < 192) {
        int c = tid * 4;
        float4 gv = *(const float4*)(g + c);
        float4 bv = *(const float4*)(b + c);
        __hip_bfloat16 h0 = __float2bfloat16((v.x - mu) * rs * gv.x + bv.x);
        __hip_bfloat16 h1 = __float2bfloat16((v.y - mu) * rs * gv.y + bv.y);
        __hip_bfloat16 h2 = __float2bfloat16((v.z - mu) * rs * gv.z + bv.z);
        __hip_bfloat16 h3 = __float2bfloat16((v.w - mu) * rs * gv.w + bv.w);
        ushort4 pack;
        pack.x = *reinterpret_cast<unsigned short*>(&h0);
        pack.y = *reinterpret_cast<unsigned short*>(&h1);
        pack.z = *reinterpret_cast<unsigned short*>(&h2);
        pack.w = *reinterpret_cast<unsigned short*>(&h3);
        *(ushort4*)(yn + (size_t)row * NE + c) = pack;
    }
}

extern "C" void kernel_launch(void* const* d_in, const int* in_sizes, int n_in,
                              void* d_out, int out_size, void* d_ws, size_t ws_size,
                              hipStream_t stream)
{
    const int*   idx  = (const int*)  d_in[0];
    const float* tok  = (const float*)d_in[1];
    const float* pos  = (const float*)d_in[2];
    const float* Wq   = (const float*)d_in[3];
    const float* bq   = (const float*)d_in[4];
    const float* Wk   = (const float*)d_in[5];
    const float* bk   = (const float*)d_in[6];
    const float* Wv   = (const float*)d_in[7];
    const float* bv   = (const float*)d_in[8];
    const float* ln_g = (const float*)d_in[9];
    const float* ln_b = (const float*)d_in[10];
    const float* Wh   = (const float*)d_in[11];
    const float* bh   = (const float*)d_in[12];
    float* out = (float*)d_out;

    const int B = 4, T = 2048, C = 768, V = 50257, Vp = 50432;  // Vp = 197*256 = 788*64

    char* p = (char*)d_ws;
    auto take = [&](size_t bytes) { char* r = p; p += (bytes + 255) & ~(size_t)255; return r; };
    __hip_bfloat16* xb    = (__hip_bfloat16*)take((size_t)B * T * C * 2);
    __hip_bfloat16* wqkvT = (__hip_bfloat16*)take((size_t)3 * C * C * 2);
    float*          bqkv  = (float*)take((size_t)3 * C * 4);
    __hip_bfloat16* qb    = (__hip_bfloat16*)take((size_t)B * T * C * 2);
    __hip_bfloat16* kb    = (__hip_bfloat16*)take((size_t)B * T * C * 2);
    __hip_bfloat16* vb    = (__hip_bfloat16*)take((size_t)B * T * C * 2);
    __hip_bfloat16* vT    = (__hip_bfloat16*)take((size_t)B * T * C * 2);
    float*          att   = (float*)take((size_t)B * T * T * 4);
    __hip_bfloat16* P     = (__hip_bfloat16*)take((size_t)B * T * T * 2);
    float*          y     = (float*)take((size_t)B * T * C * 4);
    __hip_bfloat16* yn    = (__hip_bfloat16*)take((size_t)B * T * C * 2);
    // Wh^T (77.4 MB, Vp rows) reuses the att+P region (100.6 MB) — dead once y exists.
    __hip_bfloat16* whT   = (__hip_bfloat16*)att;

    float scale = 1.0f / sqrtf((float)C);

    k_embed<<<dim3(B * T), 256, 0, stream>>>(idx, tok, pos, xb);
    k_transpose_f32_bf16<<<dim3(24, 24), 256, 0, stream>>>(Wq, wqkvT,             C, C, C);
    k_transpose_f32_bf16<<<dim3(24, 24), 256, 0, stream>>>(Wk, wqkvT + C * C,     C, C, C);
    k_transpose_f32_bf16<<<dim3(24, 24), 256, 0, stream>>>(Wv, wqkvT + 2 * C * C, C, C, C);
    k_pack_bias<<<dim3(9), 256, 0, stream>>>(bq, bk, bv, bqkv);

    // qkv: [8192,768] x [2304,768]^T, 8-phase kernel
    k_gemm8<0><<<dim3(9, 32, 1), 512, 0, stream>>>(xb, wqkvT, nullptr, 0, 2304,
        bqkv, 1.f, qb, kb, vb, 0, 0, 0);

    k_transpose_bf16<<<dim3(24, 64, B), 256, 0, stream>>>(vb, vT, T, C);

    // att = q k^T / sqrt(C): per batch [2048,768] x [2048,768]^T, 8-phase, causal skip
    k_gemm8<1><<<dim3(8, 8, B), 512, 0, stream>>>(qb, kb, att, T, T,
        nullptr, scale, nullptr, nullptr, nullptr,
        (size_t)T * C, (size_t)T * C, (size_t)T * T);

    k_softmax<<<dim3(T, B), 256, 0, stream>>>(att, P, T);

    // y = P v: per batch [2048,2048] x [768,2048]^T, causal-truncated dbuf kernel
    k_gemm_pv<<<dim3(6, 16, B), 256, 0, stream>>>(P, vT, y);

    // Wh^T after PV so it can overwrite att/P scratch (vectorized transpose)
    k_transpose_wh<<<dim3(Vp / 64, C / 64), 256, 0, stream>>>(Wh, whT, C, V);

    k_layernorm<<<dim3(B * T), 256, 0, stream>>>(y, ln_g, ln_b, yn);

    // logits: [8192,768] x [50432,768]^T -> fp32 d_out; R13 8-phase + XCD swizzle
    k_gemm8<3><<<dim3(Vp / 256, 32), 512, 0, stream>>>(yn, whT, out, V, V,
        bh, 1.f, nullptr, nullptr, nullptr, 0, 0, 0);
}

// Round 17
// 1147.661 us; speedup vs baseline: 1.4323x; 1.0093x over previous
//
#include <hip/hip_runtime.h>
#include <hip/hip_bf16.h>
#include <math.h>

typedef __bf16 bf16x8 __attribute__((ext_vector_type(8)));
typedef float  f32x4  __attribute__((ext_vector_type(4)));

#define GAS(p) ((const __attribute__((address_space(1))) void*)(p))
#define LAS(p) ((__attribute__((address_space(3))) void*)(p))

static constexpr int NE = 768;

// ---------------- embed: x = tok_emb[idx] + pos_emb, -> bf16; 2 rows/block ----------------
__global__ __launch_bounds__(256) void k_embed(const int* __restrict__ idx,
    const float* __restrict__ tok, const float* __restrict__ pos,
    __hip_bfloat16* __restrict__ xb)
{
    int tid = threadIdx.x;
    if (tid >= 192) return;
    int bt = blockIdx.x * 2 + (tid / 96);   // 0..8191
    int lane = tid % 96;
    int t  = bt & 2047;
    int token = idx[bt];
    const float* te = tok + (size_t)token * NE;
    const float* pe = pos + (size_t)t * NE;
    __hip_bfloat16* o = xb + (size_t)bt * NE;
    int c = lane * 8;
    float4 a0 = *(const float4*)(te + c),     p0 = *(const float4*)(pe + c);
    float4 a1 = *(const float4*)(te + c + 4), p1 = *(const float4*)(pe + c + 4);
    float s[8] = { a0.x + p0.x, a0.y + p0.y, a0.z + p0.z, a0.w + p0.w,
                   a1.x + p1.x, a1.y + p1.y, a1.z + p1.z, a1.w + p1.w };
    bf16x8 v;
    #pragma unroll
    for (int j = 0; j < 8; ++j) {
        __hip_bfloat16 h = __float2bfloat16(s[j]);
        v[j] = *reinterpret_cast<__bf16*>(&h);
    }
    *(bf16x8*)(o + c) = v;
}

// ------------- batched transpose fp32 [R][C] -> bf16 [C][R]: z selects (Wq,Wk,Wv) -------------
__global__ __launch_bounds__(256) void k_transpose_qkv(
    const float* __restrict__ wq, const float* __restrict__ wk, const float* __restrict__ wv,
    __hip_bfloat16* __restrict__ out /* [3][768][768] */)
{
    __shared__ float tile[32][33];
    const float* in = (blockIdx.z == 0) ? wq : (blockIdx.z == 1) ? wk : wv;
    __hip_bfloat16* o = out + (size_t)blockIdx.z * NE * NE;
    int c0 = blockIdx.x * 32, r0 = blockIdx.y * 32;
    int tx = threadIdx.x & 31, ty = threadIdx.x >> 5;
    #pragma unroll
    for (int i = 0; i < 32; i += 8)
        tile[ty + i][tx] = in[(size_t)(r0 + ty + i) * NE + (c0 + tx)];
    __syncthreads();
    #pragma unroll
    for (int i = 0; i < 32; i += 8)
        o[(size_t)(c0 + ty + i) * NE + (r0 + tx)] = __float2bfloat16(tile[tx][ty + i]);
}

// ------------- Wh transpose: fp32 [768][50257] -> bf16 [50432][768], vectorized -------------
__global__ __launch_bounds__(256) void k_transpose_wh(
    const float* __restrict__ in, __hip_bfloat16* __restrict__ out,
    int R /*768*/, int C /*50257*/)
{
    __shared__ float tile[64][65];
    const int n0 = blockIdx.x * 64, k0 = blockIdx.y * 64;
    const int t = threadIdx.x;
    if (n0 + 64 <= C) {              // fast path: full float4 tile
        #pragma unroll
        for (int pass = 0; pass < 4; ++pass) {
            int idx = pass * 256 + t;
            int kr = idx >> 4, nc4 = (idx & 15) * 4;
            float4 v = *(const float4*)(in + (size_t)(k0 + kr) * C + n0 + nc4);
            tile[kr][nc4] = v.x; tile[kr][nc4 + 1] = v.y;
            tile[kr][nc4 + 2] = v.z; tile[kr][nc4 + 3] = v.w;
        }
    } else {                         // boundary: guarded scalar
        #pragma unroll
        for (int pass = 0; pass < 16; ++pass) {
            int idx = pass * 256 + t;
            int kr = idx >> 6, nc = idx & 63;
            int c = n0 + nc;
            tile[kr][nc] = (c < C) ? in[(size_t)(k0 + kr) * C + c] : 0.f;
        }
    }
    __syncthreads();
    #pragma unroll
    for (int pass = 0; pass < 2; ++pass) {
        int nr = pass * 32 + (t >> 3);
        int kc = (t & 7) * 8;
        bf16x8 v;
        #pragma unroll
        for (int j = 0; j < 8; ++j) {
            __hip_bfloat16 h = __float2bfloat16(tile[kc + j][nr]);
            v[j] = *reinterpret_cast<__bf16*>(&h);
        }
        *(bf16x8*)(out + (size_t)(n0 + nr) * R + k0 + kc) = v;
    }
}

// ------------- batched bf16 transpose: in [z][R][C] -> out [z][C][R] -------------
__global__ __launch_bounds__(256) void k_transpose_bf16(
    const __hip_bfloat16* __restrict__ in, __hip_bfloat16* __restrict__ out,
    int R, int C)
{
    __shared__ __hip_bfloat16 tile[32][33];
    size_t boff = (size_t)blockIdx.z * R * C;
    int c0 = blockIdx.x * 32, r0 = blockIdx.y * 32;
    int tx = threadIdx.x & 31, ty = threadIdx.x >> 5;
    #pragma unroll
    for (int i = 0; i < 32; i += 8)
        tile[ty + i][tx] = in[boff + (size_t)(r0 + ty + i) * C + (c0 + tx)];
    __syncthreads();
    #pragma unroll
    for (int i = 0; i < 32; i += 8)
        out[boff + (size_t)(c0 + ty + i) * R + (r0 + tx)] = tile[tx][ty + i];
}

__global__ __launch_bounds__(256) void k_pack_bias(const float* __restrict__ bq,
    const float* __restrict__ bk, const float* __restrict__ bv, float* __restrict__ o)
{
    int i = blockIdx.x * 256 + threadIdx.x;
    if (i < 768) o[i] = bq[i];
    else if (i < 1536) o[i] = bk[i - 768];
    else if (i < 2304) o[i] = bv[i - 1536];
}

// ================= PV GEMM: 128x128, BK=64, dbuf, counted vmcnt, 2 blocks/CU =================
__global__ __launch_bounds__(256, 2) void k_gemm_pv(
    const __hip_bfloat16* __restrict__ Pm,  // [B][2048][2048]
    const __hip_bfloat16* __restrict__ Vt,  // [B][768][2048]
    float* __restrict__ y)                  // [B][2048][768]
{
    constexpr int T = 2048, C = 768;
    __shared__ __align__(16) __hip_bfloat16 As[2][128 * 64];
    __shared__ __align__(16) __hip_bfloat16 Bs[2][128 * 64];

    const int bn = blockIdx.x;                              // 0..5
    const int bm = (int)gridDim.y - 1 - (int)blockIdx.y;    // longest-first
    const int bz = blockIdx.z;
    const int NT = (bm + 1) * 2;                            // K-tiles of 64
    const int tid = threadIdx.x;
    const int w = tid >> 6, lane = tid & 63;
    const int wr = w >> 1, wc = w & 1;                      // wave tile 64x64
    const int lr = lane & 15, lu = lane >> 4;

    const __hip_bfloat16* Ap = Pm + (size_t)bz * T * T + (size_t)(bm * 128) * T;
    const __hip_bfloat16* Bp = Vt + (size_t)bz * C * T + (size_t)(bn * 128) * T;

    f32x4 acc[4][4] = {};

    auto stage = [&](int kt, int pb) {            // 8 loads/thread: 4 A + 4 B chunks
        #pragma unroll
        for (int l = 0; l < 4; ++l) {
            int v = l * 256 + tid;
            int row = v >> 3, u = (v & 7) ^ (row & 7);
            __builtin_amdgcn_global_load_lds(GAS(Ap + (size_t)row * T + kt * 64 + u * 8),
                                             LAS(&As[pb][v * 8]), 16, 0, 0);
        }
        #pragma unroll
        for (int l = 0; l < 4; ++l) {
            int v = l * 256 + tid;
            int row = v >> 3, u = (v & 7) ^ (row & 7);
            __builtin_amdgcn_global_load_lds(GAS(Bp + (size_t)row * T + kt * 64 + u * 8),
                                             LAS(&Bs[pb][v * 8]), 16, 0, 0);
        }
    };
    auto rdA = [&](int pb, int m, int kk) {
        int row = wr * 64 + m * 16 + lr;
        return *(const bf16x8*)&As[pb][row * 64 + (((kk * 4 + lu) ^ (row & 7)) << 3)];
    };
    auto rdB = [&](int pb, int n, int kk) {
        int row = wc * 64 + n * 16 + lr;
        return *(const bf16x8*)&Bs[pb][row * 64 + (((kk * 4 + lu) ^ (row & 7)) << 3)];
    };

    stage(0, 0);
    stage(1, 1);
    asm volatile("s_waitcnt vmcnt(8)" ::: "memory");
    asm volatile("s_barrier" ::: "memory");

    for (int kt = 0; kt < NT; ++kt) {
        const int p = kt & 1;
        bf16x8 af[4][2], bfv[4][2];
        #pragma unroll
        for (int m = 0; m < 4; ++m) { af[m][0] = rdA(p, m, 0); af[m][1] = rdA(p, m, 1); }
        #pragma unroll
        for (int n = 0; n < 4; ++n) { bfv[n][0] = rdB(p, n, 0); bfv[n][1] = rdB(p, n, 1); }
        asm volatile("s_waitcnt lgkmcnt(0)" ::: "memory");  // frags in regs; buf[p] dead
        asm volatile("s_barrier" ::: "memory");             // all waves done with buf[p]
        if (kt + 2 < NT) {
            stage(kt + 2, p);
            asm volatile("s_waitcnt vmcnt(8)" ::: "memory");   // tile kt+1 landed
        } else if (kt + 1 < NT) {
            asm volatile("s_waitcnt vmcnt(0)" ::: "memory");
        }
        asm volatile("s_barrier" ::: "memory");
        __builtin_amdgcn_s_setprio(1);
        #pragma unroll
        for (int m = 0; m < 4; ++m)
            #pragma unroll
            for (int n = 0; n < 4; ++n)
                acc[m][n] = __builtin_amdgcn_mfma_f32_16x16x32_bf16(af[m][0], bfv[n][0], acc[m][n], 0, 0, 0);
        #pragma unroll
        for (int m = 0; m < 4; ++m)
            #pragma unroll
            for (int n = 0; n < 4; ++n)
                acc[m][n] = __builtin_amdgcn_mfma_f32_16x16x32_bf16(af[m][1], bfv[n][1], acc[m][n], 0, 0, 0);
        __builtin_amdgcn_s_setprio(0);
    }

    const int r4 = lu * 4;
    float* yo = y + (size_t)bz * T * C;
    #pragma unroll
    for (int m = 0; m < 4; ++m) {
        #pragma unroll
        for (int n = 0; n < 4; ++n) {
            int col = bn * 128 + wc * 64 + n * 16 + lr;
            #pragma unroll
            for (int r = 0; r < 4; ++r) {
                int row = bm * 128 + wr * 64 + m * 16 + r4 + r;
                yo[(size_t)row * C + col] = acc[m][n][r];
            }
        }
    }
}

// ================= unified 256x256 8-phase GEMM (R13 schedule, verified) =================
// MODE 0: qkv (bf16 out split q/k/v, +bias)  grid (9, 32, 1)
// MODE 1: att (fp32 out * scale, batched, causal 256-tile skip)  grid (8, 8, B)
// MODE 3: head (fp32 out + bias, col-bounded)  grid (197, 32, 1)
template<int MODE>
__global__ __launch_bounds__(512, 2) void k_gemm8(
    const __hip_bfloat16* __restrict__ A, const __hip_bfloat16* __restrict__ Bt,
    float* __restrict__ outf, int ldc, int ncols,
    const float* __restrict__ bias, float scale,
    __hip_bfloat16* __restrict__ oq, __hip_bfloat16* __restrict__ ok,
    __hip_bfloat16* __restrict__ ov,
    size_t strideA, size_t strideB, size_t strideC)
{
    constexpr int K = 768, NT = K / 64, NI = NT / 2;    // 12 tiles, 6 iters
    __shared__ __align__(16) __hip_bfloat16 As[2][2][128 * 64];  // [buf][half]
    __shared__ __align__(16) __hip_bfloat16 Bs[2][2][128 * 64];

    // bijective XCD remap of fast axis
    const int Nx = (int)gridDim.x;
    const int qq = Nx >> 3, rr = Nx & 7;
    const int xcd = (int)blockIdx.x & 7, xidx = (int)blockIdx.x >> 3;
    const int bn = (xcd < rr ? xcd * (qq + 1) : rr * (qq + 1) + (xcd - rr) * qq) + xidx;
    const int bm = blockIdx.y, bz = blockIdx.z;
    if (MODE == 1 && bn > bm) return;   // fully masked causal 256-tile
    const int tid = threadIdx.x;
    const int w = tid >> 6, lane = tid & 63;
    const int wr = w >> 2, wc = w & 3;      // wave = (M-half wr, N-quarter wc)
    const int lr = lane & 15, lu = lane >> 4;

    const int sr = tid >> 3;                // staging row within 64-row chunk
    const int su = (tid & 7) ^ (sr & 7);    // pre-swizzled source 16B unit
    const __hip_bfloat16* Ap = A  + bz * strideA + (size_t)(bm * 256) * K;
    const __hip_bfloat16* Bp = Bt + bz * strideB + (size_t)(bn * 256) * K;

    f32x4 acc[8][4] = {};
    bf16x8 bq[4][2];

    auto stageAh = [&](int t, int h) {      // A half h (128 rows x 64) -> buf t&1
        #pragma unroll
        for (int l = 0; l < 2; ++l)
            __builtin_amdgcn_global_load_lds(
                GAS(Ap + (size_t)(h * 128 + l * 64 + sr) * K + t * 64 + su * 8),
                LAS(&As[t & 1][h][l * 4096 + tid * 8]), 16, 0, 0);
    };
    auto stageBh = [&](int t, int h) {
        #pragma unroll
        for (int l = 0; l < 2; ++l)
            __builtin_amdgcn_global_load_lds(
                GAS(Bp + (size_t)(h * 128 + l * 64 + sr) * K + t * 64 + su * 8),
                LAS(&Bs[t & 1][h][l * 4096 + tid * 8]), 16, 0, 0);
    };
    auto rdA = [&](int b, int q, int f, int kk) {   // wave wr reads only A-half wr
        int row = q * 32 + f * 16 + lr;
        return *(const bf16x8*)&As[b][wr][row * 64 + (((kk * 4 + lu) ^ (row & 7)) << 3)];
    };
    auto rdB = [&](int b, int n, int kk) {          // wave wc reads only B-half wc>>1
        int row = (wc & 1) * 64 + n * 16 + lr;
        return *(const bf16x8*)&Bs[b][wc >> 1][row * 64 + (((kk * 4 + lu) ^ (row & 7)) << 3)];
    };

#define BAR() asm volatile("s_barrier" ::: "memory")
#define VM4() asm volatile("s_waitcnt vmcnt(4)" ::: "memory")
#define VM0() asm volatile("s_waitcnt vmcnt(0)" ::: "memory")
#define CLUSTER(Q)                                                                                          \
    __builtin_amdgcn_s_setprio(1);                                                                          \
    _Pragma("unroll") for (int n = 0; n < 4; ++n)                                                           \
        acc[2*(Q)+0][n] = __builtin_amdgcn_mfma_f32_16x16x32_bf16(af[0][0], bq[n][0], acc[2*(Q)+0][n], 0, 0, 0); \
    _Pragma("unroll") for (int n = 0; n < 4; ++n)                                                           \
        acc[2*(Q)+1][n] = __builtin_amdgcn_mfma_f32_16x16x32_bf16(af[1][0], bq[n][0], acc[2*(Q)+1][n], 0, 0, 0); \
    _Pragma("unroll") for (int n = 0; n < 4; ++n)                                                           \
        acc[2*(Q)+0][n] = __builtin_amdgcn_mfma_f32_16x16x32_bf16(af[0][1], bq[n][1], acc[2*(Q)+0][n], 0, 0, 0); \
    _Pragma("unroll") for (int n = 0; n < 4; ++n)                                                           \
        acc[2*(Q)+1][n] = __builtin_amdgcn_mfma_f32_16x16x32_bf16(af[1][1], bq[n][1], acc[2*(Q)+1][n], 0, 0, 0); \
    __builtin_amdgcn_s_setprio(0);
#define PH(B_, Q_, STAGE)                                                       \
    {   bf16x8 af[2][2];                                                        \
        _Pragma("unroll") for (int f = 0; f < 2; ++f) {                         \
            af[f][0] = rdA(B_, Q_, f, 0); af[f][1] = rdA(B_, Q_, f, 1); }       \
        STAGE                                                                   \
        CLUSTER(Q_)                                                             \
        BAR(); }
#define PHV(B_, Q_, STAGE, VMSTMT)                                              \
    {   bf16x8 af[2][2];                                                        \
        _Pragma("unroll") for (int f = 0; f < 2; ++f) {                         \
            af[f][0] = rdA(B_, Q_, f, 0); af[f][1] = rdA(B_, Q_, f, 1); }       \
        STAGE                                                                   \
        VMSTMT                                                                  \
        BAR();                                                                  \
        CLUSTER(Q_)                                                             \
        BAR(); }

    // prologue: B(0),A(0),B(1) = 12 loads; VM4 retires tile-0's 8, leaves B(1)'s 4
    stageBh(0, 0); stageBh(0, 1);
    stageAh(0, 0); stageAh(0, 1);
    stageBh(1, 0); stageBh(1, 1);
    VM4();
    BAR();

    for (int i = 0; i < NI; ++i) {
        const int t0 = 2 * i, t1 = 2 * i + 1;
        const bool full = (i + 1 < NI);
        // ---- tile t0 (buf 0) ----
        #pragma unroll
        for (int n = 0; n < 4; ++n) { bq[n][0] = rdB(0, n, 0); bq[n][1] = rdB(0, n, 1); }
        PH(0, 0, { stageAh(t1, 0); stageAh(t1, 1); })
        PH(0, 1, { if (full) stageBh(t0 + 2, 0); })
        PH(0, 2, { if (full) stageBh(t0 + 2, 1); })
        PHV(0, 3, { }, { if (full) { VM4(); } else { VM0(); } })
        // ---- tile t1 (buf 1) ----
        #pragma unroll
        for (int n = 0; n < 4; ++n) { bq[n][0] = rdB(1, n, 0); bq[n][1] = rdB(1, n, 1); }
        PH(1, 0, { if (full) stageAh(t0 + 2, 0); })
        PH(1, 1, { if (full) stageAh(t0 + 2, 1); })
        PH(1, 2, { if (full) stageBh(t1 + 2, 0); })
        PHV(1, 3, { if (full) stageBh(t1 + 2, 1); }, { if (full) { VM4(); } else { VM0(); } })
    }
#undef PHV
#undef PH
#undef CLUSTER
#undef VM0
#undef VM4
#undef BAR

    // epilogue: row = bm*256 + wr*128 + m*16 + lu*4 + r, col = bn*256 + wc*64 + n*16 + lr
    const int r4 = lu * 4;
    #pragma unroll
    for (int m = 0; m < 8; ++m) {
        #pragma unroll
        for (int n = 0; n < 4; ++n) {
            int col = bn * 256 + wc * 64 + n * 16 + lr;
            if constexpr (MODE == 0) {
                float bv_ = bias[col];
                #pragma unroll
                for (int r = 0; r < 4; ++r) {
                    int row = bm * 256 + wr * 128 + m * 16 + r4 + r;
                    __hip_bfloat16 h = __float2bfloat16(acc[m][n][r] + bv_);
                    if (col < 768)       oq[(size_t)row * 768 + col]          = h;
                    else if (col < 1536) ok[(size_t)row * 768 + (col - 768)]  = h;
                    else                 ov[(size_t)row * 768 + (col - 1536)] = h;
                }
            } else if constexpr (MODE == 1) {
                #pragma unroll
                for (int r = 0; r < 4; ++r) {
                    int row = bm * 256 + wr * 128 + m * 16 + r4 + r;
                    outf[bz * strideC + (size_t)row * ldc + col] = acc[m][n][r] * scale;
                }
            } else {
                if (col < ncols) {
                    float bv_ = bias[col];
                    #pragma unroll
                    for (int r = 0; r < 4; ++r) {
                        int row = bm * 256 + wr * 128 + m * 16 + r4 + r;
                        outf[(size_t)row * ldc + col] = acc[m][n][r] + bv_;
                    }
                }
            }
        }
    }
}

// ---------------- causal softmax: conditional float4 loads, __expf, zero-fill to 128 ----------------
__global__ __launch_bounds__(256) void k_softmax(const float* __restrict__ att,
    __hip_bfloat16* __restrict__ P, int T)
{
    int t = blockIdx.x, b = blockIdx.y;
    const float* row = att + ((size_t)b * T + t) * T;
    __hip_bfloat16* prow = P + ((size_t)b * T + t) * T;
    const int n = t + 1;
    const int nz = ((t >> 7) + 1) << 7;     // PV (truncated, 128-tiles) reads only cols < nz
    __shared__ float red[256];
    float4 v[2];
    float mx = -1e30f;
    #pragma unroll
    for (int j = 0; j < 2; ++j) {
        int e = (threadIdx.x + j * 256) * 4;
        v[j] = (e < n) ? *(const float4*)(row + e) : make_float4(0.f, 0.f, 0.f, 0.f);
        #pragma unroll
        for (int k = 0; k < 4; ++k)
            if (e + k < n) mx = fmaxf(mx, ((const float*)&v[j])[k]);
    }
    red[threadIdx.x] = mx; __syncthreads();
    for (int o = 128; o > 0; o >>= 1) {
        if (threadIdx.x < o) red[threadIdx.x] = fmaxf(red[threadIdx.x], red[threadIdx.x + o]);
        __syncthreads();
    }
    mx = red[0]; __syncthreads();
    float ev[8];
    float sum = 0.f;
    #pragma unroll
    for (int j = 0; j < 2; ++j) {
        int e = (threadIdx.x + j * 256) * 4;
        #pragma unroll
        for (int k = 0; k < 4; ++k) {
            float x = ((const float*)&v[j])[k];
            float ex = (e + k < n) ? __expf(x - mx) : 0.f;
            ev[j * 4 + k] = ex;
            sum += ex;
        }
    }
    red[threadIdx.x] = sum; __syncthreads();
    for (int o = 128; o > 0; o >>= 1) {
        if (threadIdx.x < o) red[threadIdx.x] += red[threadIdx.x + o];
        __syncthreads();
    }
    float inv = 1.f / red[0];
    #pragma unroll
    for (int j = 0; j < 2; ++j) {
        int e = (threadIdx.x + j * 256) * 4;
        #pragma unroll
        for (int k = 0; k < 4; ++k)
            if (e + k < nz) prow[e + k] = __float2bfloat16(ev[j * 4 + k] * inv);
    }
}

// ---------------- LayerNorm (eps 1e-5) fp32 -> bf16, float4 loads + register stash ----------------
__global__ __launch_bounds__(256) void k_layernorm(const float* __restrict__ y,
    const float* __restrict__ g, const float* __restrict__ b,
    __hip_bfloat16* __restrict__ yn)
{
    int row = blockIdx.x;
    const float* yr = y + (size_t)row * NE;
    int tid = threadIdx.x;
    float4 v = make_float4(0.f, 0.f, 0.f, 0.f);
    float s = 0.f, s2 = 0.f;
    if (tid < 192) {                       // 192 x 4 = 768
        v = *(const float4*)(yr + tid * 4);
        s  = v.x + v.y + v.z + v.w;
        s2 = v.x * v.x + v.y * v.y + v.z * v.z + v.w * v.w;
    }
    __shared__ float r1[256], r2[256];
    r1[tid] = s; r2[tid] = s2; __syncthreads();
    for (int o = 128; o > 0; o >>= 1) {
        if (tid < o) { r1[tid] += r1[tid + o]; r2[tid] += r2[tid + o]; }
        __syncthreads();
    }
    float mu = r1[0] / NE;
    float var = r2[0] / NE - mu * mu;
    float rs = rsqrtf(var + 1e-5f);
    if (tid < 192) {
        int c = tid * 4;
        float4 gv = *(const float4*)(g + c);
        float4 bv = *(const float4*)(b + c);
        __hip_bfloat16 h0 = __float2bfloat16((v.x - mu) * rs * gv.x + bv.x);
        __hip_bfloat16 h1 = __float2bfloat16((v.y - mu) * rs * gv.y + bv.y);
        __hip_bfloat16 h2 = __float2bfloat16((v.z - mu) * rs * gv.z + bv.z);
        __hip_bfloat16 h3 = __float2bfloat16((v.w - mu) * rs * gv.w + bv.w);
        ushort4 pack;
        pack.x = *reinterpret_cast<unsigned short*>(&h0);
        pack.y = *reinterpret_cast<unsigned short*>(&h1);
        pack.z = *reinterpret_cast<unsigned short*>(&h2);
        pack.w = *reinterpret_cast<unsigned short*>(&h3);
        *(ushort4*)(yn + (size_t)row * NE + c) = pack;
    }
}

extern "C" void kernel_launch(void* const* d_in, const int* in_sizes, int n_in,
                              void* d_out, int out_size, void* d_ws, size_t ws_size,
                              hipStream_t stream)
{
    const int*   idx  = (const int*)  d_in[0];
    const float* tok  = (const float*)d_in[1];
    const float* pos  = (const float*)d_in[2];
    const float* Wq   = (const float*)d_in[3];
    const float* bq   = (const float*)d_in[4];
    const float* Wk   = (const float*)d_in[5];
    const float* bk   = (const float*)d_in[6];
    const float* Wv   = (const float*)d_in[7];
    const float* bv   = (const float*)d_in[8];
    const float* ln_g = (const float*)d_in[9];
    const float* ln_b = (const float*)d_in[10];
    const float* Wh   = (const float*)d_in[11];
    const float* bh   = (const float*)d_in[12];
    float* out = (float*)d_out;

    const int B = 4, T = 2048, C = 768, V = 50257, Vp = 50432;  // Vp = 197*256 = 788*64

    char* p = (char*)d_ws;
    auto take = [&](size_t bytes) { char* r = p; p += (bytes + 255) & ~(size_t)255; return r; };
    __hip_bfloat16* xb    = (__hip_bfloat16*)take((size_t)B * T * C * 2);
    __hip_bfloat16* wqkvT = (__hip_bfloat16*)take((size_t)3 * C * C * 2);
    float*          bqkv  = (float*)take((size_t)3 * C * 4);
    __hip_bfloat16* qb    = (__hip_bfloat16*)take((size_t)B * T * C * 2);
    __hip_bfloat16* kb    = (__hip_bfloat16*)take((size_t)B * T * C * 2);
    __hip_bfloat16* vb    = (__hip_bfloat16*)take((size_t)B * T * C * 2);
    __hip_bfloat16* vT    = (__hip_bfloat16*)take((size_t)B * T * C * 2);
    float*          att   = (float*)take((size_t)B * T * T * 4);
    __hip_bfloat16* P     = (__hip_bfloat16*)take((size_t)B * T * T * 2);
    float*          y     = (float*)take((size_t)B * T * C * 4);
    __hip_bfloat16* yn    = (__hip_bfloat16*)take((size_t)B * T * C * 2);
    // Wh^T (77.4 MB, Vp rows) reuses the att+P region (100.6 MB) — dead once y exists.
    __hip_bfloat16* whT   = (__hip_bfloat16*)att;

    float scale = 1.0f / sqrtf((float)C);

    k_embed<<<dim3(B * T / 2), 256, 0, stream>>>(idx, tok, pos, xb);
    k_transpose_qkv<<<dim3(24, 24, 3), 256, 0, stream>>>(Wq, Wk, Wv, wqkvT);
    k_pack_bias<<<dim3(9), 256, 0, stream>>>(bq, bk, bv, bqkv);

    // qkv: [8192,768] x [2304,768]^T, 8-phase kernel
    k_gemm8<0><<<dim3(9, 32, 1), 512, 0, stream>>>(xb, wqkvT, nullptr, 0, 2304,
        bqkv, 1.f, qb, kb, vb, 0, 0, 0);

    k_transpose_bf16<<<dim3(24, 64, B), 256, 0, stream>>>(vb, vT, T, C);

    // att = q k^T / sqrt(C): per batch [2048,768] x [2048,768]^T, 8-phase, causal skip
    k_gemm8<1><<<dim3(8, 8, B), 512, 0, stream>>>(qb, kb, att, T, T,
        nullptr, scale, nullptr, nullptr, nullptr,
        (size_t)T * C, (size_t)T * C, (size_t)T * T);

    k_softmax<<<dim3(T, B), 256, 0, stream>>>(att, P, T);

    // y = P v: per batch [2048,2048] x [768,2048]^T, causal-truncated dbuf kernel
    k_gemm_pv<<<dim3(6, 16, B), 256, 0, stream>>>(P, vT, y);

    // Wh^T after PV so it can overwrite att/P scratch (vectorized transpose)
    k_transpose_wh<<<dim3(Vp / 64, C / 64), 256, 0, stream>>>(Wh, whT, C, V);

    k_layernorm<<<dim3(B * T), 256, 0, stream>>>(y, ln_g, ln_b, yn);

    // logits: [8192,768] x [50432,768]^T -> fp32 d_out; R13 8-phase + XCD swizzle
    k_gemm8<3><<<dim3(Vp / 256, 32), 512, 0, stream>>>(yn, whT, out, V, V,
        bh, 1.f, nullptr, nullptr, nullptr, 0, 0, 0);
}